// Round 8
// baseline (235.941 us; speedup 1.0000x reference)
//
#include <hip/hip_runtime.h>
#include <hip/hip_bf16.h>

#define IN_DIM 512
#define HEADS 8
#define HID 8
#define OUT_DIM 7
#define NEG_SLOPE 0.2f

// ---------------- GEMM1: h1 = x @ W1  (+ fused asrc1/adst1) ----------------
// 64x64 tile, BK=32, 4x4 register tile, double-buffered LDS, split staging:
// issue next tile's global loads BEFORE compute, ds_write after, 1 barrier/tile.
#define BM 64
#define BK 32
#define NT (IN_DIM / BK)
__global__ __launch_bounds__(256) void gemm1_kernel(
    const float* __restrict__ x, const float* __restrict__ W1,
    const float* __restrict__ as1, const float* __restrict__ ad1,
    float* __restrict__ h1, float* __restrict__ asrc1, float* __restrict__ adst1,
    int n)
{
    __shared__ float Xt[2][BK][BM + 4];
    __shared__ float Ws[2][BK][64];
    int t = threadIdx.x;
    int col4 = (t & 15) * 4;
    int row4 = (t >> 4) * 4;
    int r0 = blockIdx.x * BM;
    int srow = t >> 3, skq = t & 7;          // staging: rows srow, srow+32; kq chunk
    const float* xa_p = x + (size_t)(r0 + srow) * IN_DIM + skq * 4;
    const float* xb_p = x + (size_t)(r0 + srow + 32) * IN_DIM + skq * 4;
    bool va = (r0 + srow) < n, vb = (r0 + srow + 32) < n;
    float acc[4][4] = {{0.f,0.f,0.f,0.f},{0.f,0.f,0.f,0.f},{0.f,0.f,0.f,0.f},{0.f,0.f,0.f,0.f}};

    float4 wa, wb, xa, xb;
    // load tile 0
    {
        const float4* w4 = (const float4*)(W1 + 0);
        wa = w4[t]; wb = w4[t + 256];
        xa = va ? *(const float4*)(xa_p) : make_float4(0,0,0,0);
        xb = vb ? *(const float4*)(xb_p) : make_float4(0,0,0,0);
    }
    // write tile 0
    {
        float4* ws4 = (float4*)(&Ws[0][0][0]);
        ws4[t] = wa; ws4[t + 256] = wb;
        Xt[0][skq*4+0][srow] = xa.x; Xt[0][skq*4+1][srow] = xa.y;
        Xt[0][skq*4+2][srow] = xa.z; Xt[0][skq*4+3][srow] = xa.w;
        Xt[0][skq*4+0][srow+32] = xb.x; Xt[0][skq*4+1][srow+32] = xb.y;
        Xt[0][skq*4+2][srow+32] = xb.z; Xt[0][skq*4+3][srow+32] = xb.w;
    }
    __syncthreads();

    int cur = 0;
    for (int tile = 0; tile < NT; ++tile) {
        // issue next tile's global loads (latency hides under compute)
        if (tile + 1 < NT) {
            int k0n = (tile + 1) * BK;
            const float4* w4 = (const float4*)(W1 + k0n * 64);
            wa = w4[t]; wb = w4[t + 256];
            xa = va ? *(const float4*)(xa_p + k0n) : make_float4(0,0,0,0);
            xb = vb ? *(const float4*)(xb_p + k0n) : make_float4(0,0,0,0);
        }
        // compute current tile
        #pragma unroll
        for (int kk = 0; kk < BK; ++kk) {
            float4 xv = *(const float4*)(&Xt[cur][kk][row4]);
            float4 wv = *(const float4*)(&Ws[cur][kk][col4]);
            acc[0][0] = fmaf(xv.x, wv.x, acc[0][0]);
            acc[0][1] = fmaf(xv.x, wv.y, acc[0][1]);
            acc[0][2] = fmaf(xv.x, wv.z, acc[0][2]);
            acc[0][3] = fmaf(xv.x, wv.w, acc[0][3]);
            acc[1][0] = fmaf(xv.y, wv.x, acc[1][0]);
            acc[1][1] = fmaf(xv.y, wv.y, acc[1][1]);
            acc[1][2] = fmaf(xv.y, wv.z, acc[1][2]);
            acc[1][3] = fmaf(xv.y, wv.w, acc[1][3]);
            acc[2][0] = fmaf(xv.z, wv.x, acc[2][0]);
            acc[2][1] = fmaf(xv.z, wv.y, acc[2][1]);
            acc[2][2] = fmaf(xv.z, wv.z, acc[2][2]);
            acc[2][3] = fmaf(xv.z, wv.w, acc[2][3]);
            acc[3][0] = fmaf(xv.w, wv.x, acc[3][0]);
            acc[3][1] = fmaf(xv.w, wv.y, acc[3][1]);
            acc[3][2] = fmaf(xv.w, wv.z, acc[3][2]);
            acc[3][3] = fmaf(xv.w, wv.w, acc[3][3]);
        }
        // write next tile into the other buffer
        if (tile + 1 < NT) {
            int nb = cur ^ 1;
            float4* ws4 = (float4*)(&Ws[nb][0][0]);
            ws4[t] = wa; ws4[t + 256] = wb;
            Xt[nb][skq*4+0][srow] = xa.x; Xt[nb][skq*4+1][srow] = xa.y;
            Xt[nb][skq*4+2][srow] = xa.z; Xt[nb][skq*4+3][srow] = xa.w;
            Xt[nb][skq*4+0][srow+32] = xb.x; Xt[nb][skq*4+1][srow+32] = xb.y;
            Xt[nb][skq*4+2][srow+32] = xb.z; Xt[nb][skq*4+3][srow+32] = xb.w;
        }
        __syncthreads();
        cur ^= 1;
    }

    int head = col4 >> 3;
    float4 asv = *(const float4*)(as1 + col4);
    float4 adv = *(const float4*)(ad1 + col4);
    #pragma unroll
    for (int r = 0; r < 4; ++r) {
        int gr = r0 + row4 + r;
        if (gr < n) {
            *(float4*)(h1 + (size_t)gr * 64 + col4) =
                make_float4(acc[r][0], acc[r][1], acc[r][2], acc[r][3]);
            float pa = acc[r][0] * asv.x + acc[r][1] * asv.y + acc[r][2] * asv.z + acc[r][3] * asv.w;
            float pd = acc[r][0] * adv.x + acc[r][1] * adv.y + acc[r][2] * adv.z + acc[r][3] * adv.w;
            pa += __shfl_xor(pa, 1);
            pd += __shfl_xor(pd, 1);
            if ((t & 1) == 0) {
                asrc1[gr * 8 + head] = pa;
                adst1[gr * 8 + head] = pd;
            }
        }
    }
}

// ---------------- CSR build: bucketed two-stage, 128-node buckets ----------
#define BSHIFT 7
#define BMASK 127
__global__ __launch_bounds__(256) void bucket_hist_kernel(
    const int* __restrict__ dst, int* __restrict__ bucketCounts, int E, int nbuck)
{
    __shared__ int cnt[512];
    int t = threadIdx.x;
    cnt[t] = 0; cnt[t + 256] = 0;
    __syncthreads();
    int i = blockIdx.x * blockDim.x + t;
    int stride = gridDim.x * blockDim.x;
    for (; i < E; i += stride) atomicAdd(&cnt[dst[i] >> BSHIFT], 1);
    __syncthreads();
    if (t < nbuck && cnt[t]) atomicAdd(&bucketCounts[t], cnt[t]);
    int t2 = t + 256;
    if (t2 < nbuck && cnt[t2]) atomicAdd(&bucketCounts[t2], cnt[t2]);
}

__global__ __launch_bounds__(512) void bucket_scan_kernel(
    const int* __restrict__ bucketCounts, int* __restrict__ bucketBase,
    int* __restrict__ bucketCursor, int nbuck)
{
    __shared__ int wsum[8];
    int t = threadIdx.x, lane = t & 63, w = t >> 6;
    int c = (t < nbuck) ? bucketCounts[t] : 0;
    int inc = c;
    #pragma unroll
    for (int d = 1; d < 64; d <<= 1) {
        int u = __shfl_up(inc, d);
        if (lane >= d) inc += u;
    }
    if (lane == 63) wsum[w] = inc;
    __syncthreads();
    if (t == 0) { int run = 0; for (int k = 0; k < 8; ++k) { int tmp = wsum[k]; wsum[k] = run; run += tmp; } }
    __syncthreads();
    int excl = inc - c + wsum[w];
    if (t < nbuck) { bucketBase[t] = excl; bucketCursor[t] = excl; }
    if (t == nbuck) bucketBase[t] = excl;
}

#define K3_EPT 16
__global__ __launch_bounds__(256) void coarse_scatter_kernel(
    const int* __restrict__ src, const int* __restrict__ dst,
    int* __restrict__ bucketCursor, unsigned int* __restrict__ tmp, int E)
{
    __shared__ int cnt[512];
    __shared__ int gbase[512];
    int t = threadIdx.x;
    cnt[t] = 0; cnt[t + 256] = 0;
    __syncthreads();
    int base = blockIdx.x * (256 * K3_EPT);
    unsigned int pk[K3_EPT];
    unsigned int meta[K3_EPT];   // (rank<<9)|bucket ; 0xFFFFFFFF = invalid
    #pragma unroll
    for (int j = 0; j < K3_EPT; ++j) {
        int i = base + t + j * 256;
        if (i < E) {
            int d = dst[i], s = src[i];
            int b = d >> BSHIFT;
            pk[j] = ((unsigned)s << 16) | (unsigned)(d & BMASK);
            int r = atomicAdd(&cnt[b], 1);
            meta[j] = ((unsigned)r << 9) | (unsigned)b;
        } else {
            meta[j] = 0xFFFFFFFFu; pk[j] = 0;
        }
    }
    __syncthreads();
    if (cnt[t] > 0) gbase[t] = atomicAdd(&bucketCursor[t], cnt[t]);
    int t2 = t + 256;
    if (cnt[t2] > 0) gbase[t2] = atomicAdd(&bucketCursor[t2], cnt[t2]);
    __syncthreads();
    #pragma unroll
    for (int j = 0; j < K3_EPT; ++j) {
        if (meta[j] != 0xFFFFFFFFu) {
            int b = meta[j] & 511;
            int r = meta[j] >> 9;
            tmp[gbase[b] + r] = pk[j];
        }
    }
}

__global__ __launch_bounds__(256) void fine_scatter_kernel(
    const unsigned int* __restrict__ tmp, const int* __restrict__ bucketBase,
    int* __restrict__ csr, int* __restrict__ offsets, int* __restrict__ counts, int n)
{
    __shared__ int cnt[128];
    __shared__ int cur[128];
    __shared__ int wsum[2];
    int b = blockIdx.x;
    int t = threadIdx.x, lane = t & 63, w = t >> 6;
    int beg = bucketBase[b], end = bucketBase[b + 1];
    if (t < 128) cnt[t] = 0;
    __syncthreads();
    for (int i = beg + t; i < end; i += 256)
        atomicAdd(&cnt[tmp[i] & BMASK], 1);
    __syncthreads();
    if (t < 128) {
        int c = cnt[t];
        int inc = c;
        #pragma unroll
        for (int d = 1; d < 64; d <<= 1) {
            int u = __shfl_up(inc, d);
            if (lane >= d) inc += u;
        }
        if (lane == 63) wsum[w] = inc;
        __syncthreads();
        if (t == 0) { int r0_ = wsum[0]; wsum[0] = 0; wsum[1] = r0_; }
        __syncthreads();
        int excl = inc - c + wsum[w];
        int node = b * 128 + t;
        if (node < n) { offsets[node] = beg + excl; counts[node] = c; }
        cur[t] = excl;
    } else {
        __syncthreads(); __syncthreads();
    }
    __syncthreads();
    for (int i = beg + t; i < end; i += 256) {
        unsigned int p = tmp[i];
        int r = atomicAdd(&cur[p & BMASK], 1);
        csr[beg + r] = (int)(p >> 16);
    }
}

// ---------------- Layer-1 edge kernel: single-pass (no max) ----------------
// Softmax shift-invariance: logits bounded (|e| <~ 8), exp(e) safe in f32.
// lane = quarter(2b) * 16 + il; quarter = edge slot, il*4 = channel quad.
__global__ __launch_bounds__(256) void l1_edge_kernel(
    const int* __restrict__ offsets, const int* __restrict__ counts,
    const int* __restrict__ csr,
    const float* __restrict__ asrc1, const float* __restrict__ adst1,
    const float* __restrict__ h1, const float* __restrict__ b1,
    const float* __restrict__ W2, const float* __restrict__ as2,
    const float* __restrict__ ad2,
    float* __restrict__ h2, float* __restrict__ asrc2, float* __restrict__ adst2,
    int n)
{
    __shared__ float w2t[8][64];    // transposed W2: w2t[j][c]
    __shared__ float s_as2[8], s_ad2[8], s_b1[64];
    int t = threadIdx.x;
    if (t < 64) {
        #pragma unroll
        for (int j = 0; j < OUT_DIM; ++j) w2t[j][t] = W2[t * OUT_DIM + j];
        s_b1[t] = b1[t];
        if (t < OUT_DIM) { s_as2[t] = as2[t]; s_ad2[t] = ad2[t]; }
    }
    __syncthreads();

    int lane = t & 63;
    int node = blockIdx.x * 4 + (t >> 6);
    if (node >= n) return;
    int beg = offsets[node];
    int deg = counts[node];
    int q = lane >> 4;          // quarter: edge slot
    int il = lane & 15;
    int c0 = il * 4;            // channel quad
    int head = il >> 1;
    float adv = adst1[node * 8 + head];

    float4 acc = make_float4(0.f, 0.f, 0.f, 0.f);
    float ssum = 0.f;
    if (q == 0) {   // self loop
        float e = asrc1[node * 8 + head] + adv;
        e = e > 0.f ? e : NEG_SLOPE * e;
        float p = __expf(e);
        float4 hv = *(const float4*)(h1 + (size_t)node * 64 + c0);
        acc.x = p * hv.x; acc.y = p * hv.y; acc.z = p * hv.z; acc.w = p * hv.w;
        ssum = p;
    }
    int j = q;
    for (; j + 4 < deg; j += 8) {   // 2 edges per quarter per round
        int s0 = csr[beg + j], s1 = csr[beg + j + 4];
        float a0 = asrc1[s0 * 8 + head], a1 = asrc1[s1 * 8 + head];
        float4 g0 = *(const float4*)(h1 + (size_t)s0 * 64 + c0);
        float4 g1 = *(const float4*)(h1 + (size_t)s1 * 64 + c0);
        float e0 = a0 + adv; e0 = e0 > 0.f ? e0 : NEG_SLOPE * e0;
        float e1 = a1 + adv; e1 = e1 > 0.f ? e1 : NEG_SLOPE * e1;
        float p0 = __expf(e0), p1 = __expf(e1);
        acc.x = fmaf(p0, g0.x, acc.x); acc.y = fmaf(p0, g0.y, acc.y);
        acc.z = fmaf(p0, g0.z, acc.z); acc.w = fmaf(p0, g0.w, acc.w);
        acc.x = fmaf(p1, g1.x, acc.x); acc.y = fmaf(p1, g1.y, acc.y);
        acc.z = fmaf(p1, g1.z, acc.z); acc.w = fmaf(p1, g1.w, acc.w);
        ssum += p0 + p1;
    }
    for (; j < deg; j += 4) {
        int sn = csr[beg + j];
        float a = asrc1[sn * 8 + head];
        float4 g = *(const float4*)(h1 + (size_t)sn * 64 + c0);
        float e = a + adv; e = e > 0.f ? e : NEG_SLOPE * e;
        float p = __expf(e);
        acc.x = fmaf(p, g.x, acc.x); acc.y = fmaf(p, g.y, acc.y);
        acc.z = fmaf(p, g.z, acc.z); acc.w = fmaf(p, g.w, acc.w);
        ssum += p;
    }
    // combine quarters
    acc.x += __shfl_xor(acc.x, 16); acc.x += __shfl_xor(acc.x, 32);
    acc.y += __shfl_xor(acc.y, 16); acc.y += __shfl_xor(acc.y, 32);
    acc.z += __shfl_xor(acc.z, 16); acc.z += __shfl_xor(acc.z, 32);
    acc.w += __shfl_xor(acc.w, 16); acc.w += __shfl_xor(acc.w, 32);
    ssum  += __shfl_xor(ssum, 16);  ssum  += __shfl_xor(ssum, 32);
    float inv = 1.f / fmaxf(ssum, 1e-16f);

    float4 bv = *(const float4*)(&s_b1[c0]);
    float v0 = acc.x * inv + bv.x;
    float v1 = acc.y * inv + bv.y;
    float v2 = acc.z * inv + bv.z;
    float v3 = acc.w * inv + bv.w;
    v0 = v0 > 0.f ? v0 : __expf(v0) - 1.f;
    v1 = v1 > 0.f ? v1 : __expf(v1) - 1.f;
    v2 = v2 > 0.f ? v2 : __expf(v2) - 1.f;
    v3 = v3 > 0.f ? v3 : __expf(v3) - 1.f;

    // fused GEMM2 (64 -> 7) + att2; reduce over il (16 lanes), quarters redundant
    float hj[OUT_DIM];
    #pragma unroll
    for (int jj = 0; jj < OUT_DIM; ++jj) {
        float4 wv = *(const float4*)(&w2t[jj][c0]);
        float p = v0 * wv.x + v1 * wv.y + v2 * wv.z + v3 * wv.w;
        p += __shfl_xor(p, 1);
        p += __shfl_xor(p, 2);
        p += __shfl_xor(p, 4);
        p += __shfl_xor(p, 8);
        hj[jj] = p;
    }
    float a_s = 0.f, a_d = 0.f;
    #pragma unroll
    for (int jj = 0; jj < OUT_DIM; ++jj) { a_s += hj[jj] * s_as2[jj]; a_d += hj[jj] * s_ad2[jj]; }
    if (lane < 8) h2[node * 8 + lane] = (lane < OUT_DIM) ? hj[lane] : 0.f;
    if (lane == 0) { asrc2[node] = a_s; adst2[node] = a_d; }
}

// ---------------- Layer-2 edge kernel: single-pass -> final logits --------
__global__ __launch_bounds__(256) void l2_edge_kernel(
    const int* __restrict__ offsets, const int* __restrict__ counts,
    const int* __restrict__ csr,
    const float* __restrict__ asrc2, const float* __restrict__ adst2,
    const float* __restrict__ h2, const float* __restrict__ b2,
    float* __restrict__ out, int n)
{
    int t = threadIdx.x, lane = t & 63;
    int node = blockIdx.x * 4 + (t >> 6);
    if (node >= n) return;
    int beg = offsets[node];
    int deg = counts[node];
    float adv = adst2[node];

    int c = lane & 7, slot = lane >> 3;
    float acc = 0.f, ssum = 0.f;
    if (slot == 0) {   // self loop
        float e = asrc2[node] + adv;
        e = e > 0.f ? e : NEG_SLOPE * e;
        float p = __expf(e);
        acc = p * h2[node * 8 + c];
        ssum = p;
    }
    int j = slot;
    for (; j + 8 < deg; j += 16) {
        int s0 = csr[beg + j], s1 = csr[beg + j + 8];
        float a0 = asrc2[s0], a1 = asrc2[s1];
        float g0 = h2[s0 * 8 + c], g1 = h2[s1 * 8 + c];
        float e0 = a0 + adv; e0 = e0 > 0.f ? e0 : NEG_SLOPE * e0;
        float e1 = a1 + adv; e1 = e1 > 0.f ? e1 : NEG_SLOPE * e1;
        float p0 = __expf(e0), p1 = __expf(e1);
        acc = fmaf(p0, g0, acc); acc = fmaf(p1, g1, acc);
        ssum += p0 + p1;
    }
    for (; j < deg; j += 8) {
        int sn = csr[beg + j];
        float e = asrc2[sn] + adv;
        e = e > 0.f ? e : NEG_SLOPE * e;
        float p = __expf(e);
        acc = fmaf(p, h2[sn * 8 + c], acc);
        ssum += p;
    }
    acc  += __shfl_xor(acc, 8);  acc  += __shfl_xor(acc, 16);  acc  += __shfl_xor(acc, 32);
    ssum += __shfl_xor(ssum, 8); ssum += __shfl_xor(ssum, 16); ssum += __shfl_xor(ssum, 32);
    float inv = 1.f / fmaxf(ssum, 1e-16f);
    if (lane < OUT_DIM) out[(size_t)node * OUT_DIM + lane] = acc * inv + b2[lane];
}

// ---------------- launch ----------------
static inline size_t rup256(size_t x) { return (x + 255) & ~(size_t)255; }

extern "C" void kernel_launch(void* const* d_in, const int* in_sizes, int n_in,
                              void* d_out, int out_size, void* d_ws, size_t ws_size,
                              hipStream_t stream)
{
    int n = in_sizes[0] / IN_DIM;       // 50000
    int E = in_sizes[1] / 2;            // 1600000
    int nbuck = (n + BMASK) >> BSHIFT;  // 391

    const float* x   = (const float*)d_in[0];
    const int*   ei  = (const int*)d_in[1];
    const int*   srcv = ei;
    const int*   dstv = ei + E;
    const float* W1  = (const float*)d_in[2];
    const float* as1 = (const float*)d_in[3];
    const float* ad1 = (const float*)d_in[4];
    const float* b1  = (const float*)d_in[5];
    const float* W2  = (const float*)d_in[6];
    const float* as2 = (const float*)d_in[7];
    const float* ad2 = (const float*)d_in[8];
    const float* b2  = (const float*)d_in[9];
    float* out = (float*)d_out;

    char* p = (char*)d_ws;
    auto alloc = [&](size_t bytes) { char* q = p; p += rup256(bytes); return (void*)q; };
    float* h1      = (float*)alloc((size_t)n * 64 * 4);
    float* asrc1   = (float*)alloc((size_t)n * 8 * 4);
    float* adst1   = (float*)alloc((size_t)n * 8 * 4);
    float* h2      = (float*)alloc((size_t)n * 8 * 4);
    float* asrc2   = (float*)alloc((size_t)n * 4);
    float* adst2   = (float*)alloc((size_t)n * 4);
    int*   counts  = (int*)alloc((size_t)n * 4);
    int*   offsets = (int*)alloc(((size_t)n + 1) * 4);
    int*   csr     = (int*)alloc((size_t)E * 4);
    unsigned int* tmp = (unsigned int*)alloc((size_t)E * 4);
    int*   bucketCounts = (int*)alloc(512 * 4);
    int*   bucketBase   = (int*)alloc(513 * 4);
    int*   bucketCursor = (int*)alloc(512 * 4);

    hipMemsetAsync(bucketCounts, 0, 512 * 4, stream);
    bucket_hist_kernel<<<512, 256, 0, stream>>>(dstv, bucketCounts, E, nbuck);
    gemm1_kernel<<<(n + BM - 1) / BM, 256, 0, stream>>>(
        x, W1, as1, ad1, h1, asrc1, adst1, n);
    bucket_scan_kernel<<<1, 512, 0, stream>>>(bucketCounts, bucketBase, bucketCursor, nbuck);
    coarse_scatter_kernel<<<(E + 256 * K3_EPT - 1) / (256 * K3_EPT), 256, 0, stream>>>(
        srcv, dstv, bucketCursor, tmp, E);
    fine_scatter_kernel<<<nbuck, 256, 0, stream>>>(
        tmp, bucketBase, csr, offsets, counts, n);
    l1_edge_kernel<<<(n + 3) / 4, 256, 0, stream>>>(
        offsets, counts, csr, asrc1, adst1, h1, b1, W2, as2, ad2, h2, asrc2, adst2, n);
    l2_edge_kernel<<<(n + 3) / 4, 256, 0, stream>>>(
        offsets, counts, csr, asrc2, adst2, h2, b2, out, n);
}

// Round 9
// 226.653 us; speedup vs baseline: 1.0410x; 1.0410x over previous
//
#include <hip/hip_runtime.h>
#include <hip/hip_bf16.h>

#define IN_DIM 512
#define HEADS 8
#define HID 8
#define OUT_DIM 7
#define NEG_SLOPE 0.2f

typedef __attribute__((ext_vector_type(8))) short short8b;   // 8 bf16 (4 VGPR)
typedef __attribute__((ext_vector_type(4))) float f32x4;

// ---------------- W1 split prep: W1(f32,[512][64]) -> hi/lo bf16 transposed [64][512]
__global__ __launch_bounds__(256) void w1_split_kernel(
    const float* __restrict__ W1, unsigned short* __restrict__ whiT,
    unsigned short* __restrict__ wloT)
{
    int i = blockIdx.x * 256 + threadIdx.x;   // i = k*64 + c
    if (i >= IN_DIM * 64) return;
    int k = i >> 6, c = i & 63;
    float w = W1[i];
    unsigned u = __float_as_uint(w);
    unsigned hu = u & 0xFFFF0000u;
    float rem = w - __uint_as_float(hu);
    whiT[c * IN_DIM + k] = (unsigned short)(hu >> 16);
    wloT[c * IN_DIM + k] = (unsigned short)(__float_as_uint(rem) >> 16);
}

// ---------------- GEMM1 via split-bf16 MFMA (+ fused asrc1/adst1) ----------
// Wave = 16 rows x 64 cols. A from x on the fly (hi/lo), B from whiT/wloT.
// acc = xhi*whi + xhi*wlo + xlo*whi  (xlo*wlo dropped, ~2^-16 rel).
__global__ __launch_bounds__(256) void gemm1_kernel(
    const float* __restrict__ x,
    const unsigned short* __restrict__ whiT, const unsigned short* __restrict__ wloT,
    const float* __restrict__ as1, const float* __restrict__ ad1,
    float* __restrict__ h1, float* __restrict__ asrc1, float* __restrict__ adst1,
    int n)
{
    int t = threadIdx.x;
    int wave = t >> 6, l = t & 63;
    int il = l & 15, g = l >> 4;
    int r0w = blockIdx.x * 64 + wave * 16;
    int rowA = r0w + il; if (rowA >= n) rowA = n - 1;   // clamp loads; stores guarded
    const float* xp = x + (size_t)rowA * IN_DIM + 8 * g;

    f32x4 acc[4] = {{0.f,0.f,0.f,0.f},{0.f,0.f,0.f,0.f},{0.f,0.f,0.f,0.f},{0.f,0.f,0.f,0.f}};

    for (int k0 = 0; k0 < IN_DIM; k0 += 32) {
        float4 a0 = *(const float4*)(xp + k0);
        float4 a1 = *(const float4*)(xp + k0 + 4);
        float av[8] = {a0.x, a0.y, a0.z, a0.w, a1.x, a1.y, a1.z, a1.w};
        short8b Ahi, Alo;
        #pragma unroll
        for (int j = 0; j < 8; ++j) {
            unsigned u = __float_as_uint(av[j]);
            unsigned hu = u & 0xFFFF0000u;
            float rem = av[j] - __uint_as_float(hu);
            Ahi[j] = (short)(hu >> 16);
            Alo[j] = (short)(__float_as_uint(rem) >> 16);
        }
        int bofs = k0 + 8 * g;
        #pragma unroll
        for (int T = 0; T < 4; ++T) {
            const unsigned short* bp = whiT + ((16 * T + il) * IN_DIM + bofs);
            const unsigned short* lp = wloT + ((16 * T + il) * IN_DIM + bofs);
            short8b Bhi = *(const short8b*)bp;
            short8b Blo = *(const short8b*)lp;
            acc[T] = __builtin_amdgcn_mfma_f32_16x16x32_bf16(Alo, Bhi, acc[T], 0, 0, 0);
            acc[T] = __builtin_amdgcn_mfma_f32_16x16x32_bf16(Ahi, Blo, acc[T], 0, 0, 0);
            acc[T] = __builtin_amdgcn_mfma_f32_16x16x32_bf16(Ahi, Bhi, acc[T], 0, 0, 0);
        }
    }

    // D layout (HW-verified): col = l&15 (+16T), row = 4*(l>>4) + reg.
    #pragma unroll
    for (int T = 0; T < 4; ++T) {
        float a_s = as1[16 * T + il];
        float a_d = ad1[16 * T + il];
        #pragma unroll
        for (int r = 0; r < 4; ++r) {
            int grow = r0w + 4 * g + r;
            bool ok = grow < n;
            float v = acc[T][r];
            if (ok) h1[(size_t)grow * 64 + 16 * T + il] = v;
            float pa = v * a_s, pd = v * a_d;
            pa += __shfl_xor(pa, 1); pa += __shfl_xor(pa, 2); pa += __shfl_xor(pa, 4);
            pd += __shfl_xor(pd, 1); pd += __shfl_xor(pd, 2); pd += __shfl_xor(pd, 4);
            if (ok && (il & 7) == 0) {
                int head = 2 * T + (il >> 3);
                asrc1[grow * 8 + head] = pa;
                adst1[grow * 8 + head] = pd;
            }
        }
    }
}

// ---------------- CSR build: bucketed two-stage, 128-node buckets ----------
#define BSHIFT 7
#define BMASK 127
__global__ __launch_bounds__(256) void bucket_hist_kernel(
    const int* __restrict__ dst, int* __restrict__ bucketCounts, int E, int nbuck)
{
    __shared__ int cnt[512];
    int t = threadIdx.x;
    cnt[t] = 0; cnt[t + 256] = 0;
    __syncthreads();
    int i = blockIdx.x * blockDim.x + t;
    int stride = gridDim.x * blockDim.x;
    for (; i < E; i += stride) atomicAdd(&cnt[dst[i] >> BSHIFT], 1);
    __syncthreads();
    if (t < nbuck && cnt[t]) atomicAdd(&bucketCounts[t], cnt[t]);
    int t2 = t + 256;
    if (t2 < nbuck && cnt[t2]) atomicAdd(&bucketCounts[t2], cnt[t2]);
}

__global__ __launch_bounds__(512) void bucket_scan_kernel(
    const int* __restrict__ bucketCounts, int* __restrict__ bucketBase,
    int* __restrict__ bucketCursor, int nbuck)
{
    __shared__ int wsum[8];
    int t = threadIdx.x, lane = t & 63, w = t >> 6;
    int c = (t < nbuck) ? bucketCounts[t] : 0;
    int inc = c;
    #pragma unroll
    for (int d = 1; d < 64; d <<= 1) {
        int u = __shfl_up(inc, d);
        if (lane >= d) inc += u;
    }
    if (lane == 63) wsum[w] = inc;
    __syncthreads();
    if (t == 0) { int run = 0; for (int k = 0; k < 8; ++k) { int tmp = wsum[k]; wsum[k] = run; run += tmp; } }
    __syncthreads();
    int excl = inc - c + wsum[w];
    if (t < nbuck) { bucketBase[t] = excl; bucketCursor[t] = excl; }
    if (t == nbuck) bucketBase[t] = excl;
}

#define K3_EPT 16
__global__ __launch_bounds__(256) void coarse_scatter_kernel(
    const int* __restrict__ src, const int* __restrict__ dst,
    int* __restrict__ bucketCursor, unsigned int* __restrict__ tmp, int E)
{
    __shared__ int cnt[512];
    __shared__ int gbase[512];
    int t = threadIdx.x;
    cnt[t] = 0; cnt[t + 256] = 0;
    __syncthreads();
    int base = blockIdx.x * (256 * K3_EPT);
    unsigned int pk[K3_EPT];
    unsigned int meta[K3_EPT];
    #pragma unroll
    for (int j = 0; j < K3_EPT; ++j) {
        int i = base + t + j * 256;
        if (i < E) {
            int d = dst[i], s = src[i];
            int b = d >> BSHIFT;
            pk[j] = ((unsigned)s << 16) | (unsigned)(d & BMASK);
            int r = atomicAdd(&cnt[b], 1);
            meta[j] = ((unsigned)r << 9) | (unsigned)b;
        } else {
            meta[j] = 0xFFFFFFFFu; pk[j] = 0;
        }
    }
    __syncthreads();
    if (cnt[t] > 0) gbase[t] = atomicAdd(&bucketCursor[t], cnt[t]);
    int t2 = t + 256;
    if (cnt[t2] > 0) gbase[t2] = atomicAdd(&bucketCursor[t2], cnt[t2]);
    __syncthreads();
    #pragma unroll
    for (int j = 0; j < K3_EPT; ++j) {
        if (meta[j] != 0xFFFFFFFFu) {
            int b = meta[j] & 511;
            int r = meta[j] >> 9;
            tmp[gbase[b] + r] = pk[j];
        }
    }
}

__global__ __launch_bounds__(256) void fine_scatter_kernel(
    const unsigned int* __restrict__ tmp, const int* __restrict__ bucketBase,
    int* __restrict__ csr, int* __restrict__ offsets, int* __restrict__ counts, int n)
{
    __shared__ int cnt[128];
    __shared__ int cur[128];
    __shared__ int wsum[2];
    int b = blockIdx.x;
    int t = threadIdx.x, lane = t & 63, w = t >> 6;
    int beg = bucketBase[b], end = bucketBase[b + 1];
    if (t < 128) cnt[t] = 0;
    __syncthreads();
    for (int i = beg + t; i < end; i += 256)
        atomicAdd(&cnt[tmp[i] & BMASK], 1);
    __syncthreads();
    if (t < 128) {
        int c = cnt[t];
        int inc = c;
        #pragma unroll
        for (int d = 1; d < 64; d <<= 1) {
            int u = __shfl_up(inc, d);
            if (lane >= d) inc += u;
        }
        if (lane == 63) wsum[w] = inc;
        __syncthreads();
        if (t == 0) { int r0_ = wsum[0]; wsum[0] = 0; wsum[1] = r0_; }
        __syncthreads();
        int excl = inc - c + wsum[w];
        int node = b * 128 + t;
        if (node < n) { offsets[node] = beg + excl; counts[node] = c; }
        cur[t] = excl;
    } else {
        __syncthreads(); __syncthreads();
    }
    __syncthreads();
    for (int i = beg + t; i < end; i += 256) {
        unsigned int p = tmp[i];
        int r = atomicAdd(&cur[p & BMASK], 1);
        csr[beg + r] = (int)(p >> 16);
    }
}

// ---------------- Layer-1 edge kernel: single-pass (no max) ----------------
__global__ __launch_bounds__(256) void l1_edge_kernel(
    const int* __restrict__ offsets, const int* __restrict__ counts,
    const int* __restrict__ csr,
    const float* __restrict__ asrc1, const float* __restrict__ adst1,
    const float* __restrict__ h1, const float* __restrict__ b1,
    const float* __restrict__ W2, const float* __restrict__ as2,
    const float* __restrict__ ad2,
    float* __restrict__ h2, float* __restrict__ asrc2, float* __restrict__ adst2,
    int n)
{
    __shared__ float w2t[8][64];
    __shared__ float s_as2[8], s_ad2[8], s_b1[64];
    int t = threadIdx.x;
    if (t < 64) {
        #pragma unroll
        for (int j = 0; j < OUT_DIM; ++j) w2t[j][t] = W2[t * OUT_DIM + j];
        s_b1[t] = b1[t];
        if (t < OUT_DIM) { s_as2[t] = as2[t]; s_ad2[t] = ad2[t]; }
    }
    __syncthreads();

    int lane = t & 63;
    int node = blockIdx.x * 4 + (t >> 6);
    if (node >= n) return;
    int beg = offsets[node];
    int deg = counts[node];
    int q = lane >> 4;
    int il = lane & 15;
    int c0 = il * 4;
    int head = il >> 1;
    float adv = adst1[node * 8 + head];

    float4 acc = make_float4(0.f, 0.f, 0.f, 0.f);
    float ssum = 0.f;
    if (q == 0) {
        float e = asrc1[node * 8 + head] + adv;
        e = e > 0.f ? e : NEG_SLOPE * e;
        float p = __expf(e);
        float4 hv = *(const float4*)(h1 + (size_t)node * 64 + c0);
        acc.x = p * hv.x; acc.y = p * hv.y; acc.z = p * hv.z; acc.w = p * hv.w;
        ssum = p;
    }
    int j = q;
    for (; j + 4 < deg; j += 8) {
        int s0 = csr[beg + j], s1 = csr[beg + j + 4];
        float a0 = asrc1[s0 * 8 + head], a1 = asrc1[s1 * 8 + head];
        float4 g0 = *(const float4*)(h1 + (size_t)s0 * 64 + c0);
        float4 g1 = *(const float4*)(h1 + (size_t)s1 * 64 + c0);
        float e0 = a0 + adv; e0 = e0 > 0.f ? e0 : NEG_SLOPE * e0;
        float e1 = a1 + adv; e1 = e1 > 0.f ? e1 : NEG_SLOPE * e1;
        float p0 = __expf(e0), p1 = __expf(e1);
        acc.x = fmaf(p0, g0.x, acc.x); acc.y = fmaf(p0, g0.y, acc.y);
        acc.z = fmaf(p0, g0.z, acc.z); acc.w = fmaf(p0, g0.w, acc.w);
        acc.x = fmaf(p1, g1.x, acc.x); acc.y = fmaf(p1, g1.y, acc.y);
        acc.z = fmaf(p1, g1.z, acc.z); acc.w = fmaf(p1, g1.w, acc.w);
        ssum += p0 + p1;
    }
    for (; j < deg; j += 4) {
        int sn = csr[beg + j];
        float a = asrc1[sn * 8 + head];
        float4 g = *(const float4*)(h1 + (size_t)sn * 64 + c0);
        float e = a + adv; e = e > 0.f ? e : NEG_SLOPE * e;
        float p = __expf(e);
        acc.x = fmaf(p, g.x, acc.x); acc.y = fmaf(p, g.y, acc.y);
        acc.z = fmaf(p, g.z, acc.z); acc.w = fmaf(p, g.w, acc.w);
        ssum += p;
    }
    acc.x += __shfl_xor(acc.x, 16); acc.x += __shfl_xor(acc.x, 32);
    acc.y += __shfl_xor(acc.y, 16); acc.y += __shfl_xor(acc.y, 32);
    acc.z += __shfl_xor(acc.z, 16); acc.z += __shfl_xor(acc.z, 32);
    acc.w += __shfl_xor(acc.w, 16); acc.w += __shfl_xor(acc.w, 32);
    ssum  += __shfl_xor(ssum, 16);  ssum  += __shfl_xor(ssum, 32);
    float inv = 1.f / fmaxf(ssum, 1e-16f);

    float4 bv = *(const float4*)(&s_b1[c0]);
    float v0 = acc.x * inv + bv.x;
    float v1 = acc.y * inv + bv.y;
    float v2 = acc.z * inv + bv.z;
    float v3 = acc.w * inv + bv.w;
    v0 = v0 > 0.f ? v0 : __expf(v0) - 1.f;
    v1 = v1 > 0.f ? v1 : __expf(v1) - 1.f;
    v2 = v2 > 0.f ? v2 : __expf(v2) - 1.f;
    v3 = v3 > 0.f ? v3 : __expf(v3) - 1.f;

    float hj[OUT_DIM];
    #pragma unroll
    for (int jj = 0; jj < OUT_DIM; ++jj) {
        float4 wv = *(const float4*)(&w2t[jj][c0]);
        float p = v0 * wv.x + v1 * wv.y + v2 * wv.z + v3 * wv.w;
        p += __shfl_xor(p, 1);
        p += __shfl_xor(p, 2);
        p += __shfl_xor(p, 4);
        p += __shfl_xor(p, 8);
        hj[jj] = p;
    }
    float a_s = 0.f, a_d = 0.f;
    #pragma unroll
    for (int jj = 0; jj < OUT_DIM; ++jj) { a_s += hj[jj] * s_as2[jj]; a_d += hj[jj] * s_ad2[jj]; }
    if (lane < 8) h2[node * 8 + lane] = (lane < OUT_DIM) ? hj[lane] : 0.f;
    if (lane == 0) { asrc2[node] = a_s; adst2[node] = a_d; }
}

// ---------------- Layer-2 edge kernel: single-pass -> final logits --------
__global__ __launch_bounds__(256) void l2_edge_kernel(
    const int* __restrict__ offsets, const int* __restrict__ counts,
    const int* __restrict__ csr,
    const float* __restrict__ asrc2, const float* __restrict__ adst2,
    const float* __restrict__ h2, const float* __restrict__ b2,
    float* __restrict__ out, int n)
{
    int t = threadIdx.x, lane = t & 63;
    int node = blockIdx.x * 4 + (t >> 6);
    if (node >= n) return;
    int beg = offsets[node];
    int deg = counts[node];
    float adv = adst2[node];

    int c = lane & 7, slot = lane >> 3;
    float acc = 0.f, ssum = 0.f;
    if (slot == 0) {
        float e = asrc2[node] + adv;
        e = e > 0.f ? e : NEG_SLOPE * e;
        float p = __expf(e);
        acc = p * h2[node * 8 + c];
        ssum = p;
    }
    int j = slot;
    for (; j + 8 < deg; j += 16) {
        int s0 = csr[beg + j], s1 = csr[beg + j + 8];
        float a0 = asrc2[s0], a1 = asrc2[s1];
        float g0 = h2[s0 * 8 + c], g1 = h2[s1 * 8 + c];
        float e0 = a0 + adv; e0 = e0 > 0.f ? e0 : NEG_SLOPE * e0;
        float e1 = a1 + adv; e1 = e1 > 0.f ? e1 : NEG_SLOPE * e1;
        float p0 = __expf(e0), p1 = __expf(e1);
        acc = fmaf(p0, g0, acc); acc = fmaf(p1, g1, acc);
        ssum += p0 + p1;
    }
    for (; j < deg; j += 8) {
        int sn = csr[beg + j];
        float e = asrc2[sn] + adv;
        e = e > 0.f ? e : NEG_SLOPE * e;
        float p = __expf(e);
        acc = fmaf(p, h2[sn * 8 + c], acc);
        ssum += p;
    }
    acc  += __shfl_xor(acc, 8);  acc  += __shfl_xor(acc, 16);  acc  += __shfl_xor(acc, 32);
    ssum += __shfl_xor(ssum, 8); ssum += __shfl_xor(ssum, 16); ssum += __shfl_xor(ssum, 32);
    float inv = 1.f / fmaxf(ssum, 1e-16f);
    if (lane < OUT_DIM) out[(size_t)node * OUT_DIM + lane] = acc * inv + b2[lane];
}

// ---------------- launch ----------------
static inline size_t rup256(size_t x) { return (x + 255) & ~(size_t)255; }

extern "C" void kernel_launch(void* const* d_in, const int* in_sizes, int n_in,
                              void* d_out, int out_size, void* d_ws, size_t ws_size,
                              hipStream_t stream)
{
    int n = in_sizes[0] / IN_DIM;       // 50000
    int E = in_sizes[1] / 2;            // 1600000
    int nbuck = (n + BMASK) >> BSHIFT;  // 391

    const float* x   = (const float*)d_in[0];
    const int*   ei  = (const int*)d_in[1];
    const int*   srcv = ei;
    const int*   dstv = ei + E;
    const float* W1  = (const float*)d_in[2];
    const float* as1 = (const float*)d_in[3];
    const float* ad1 = (const float*)d_in[4];
    const float* b1  = (const float*)d_in[5];
    const float* W2  = (const float*)d_in[6];
    const float* as2 = (const float*)d_in[7];
    const float* ad2 = (const float*)d_in[8];
    const float* b2  = (const float*)d_in[9];
    float* out = (float*)d_out;

    char* p = (char*)d_ws;
    auto alloc = [&](size_t bytes) { char* q = p; p += rup256(bytes); return (void*)q; };
    float* h1      = (float*)alloc((size_t)n * 64 * 4);
    float* asrc1   = (float*)alloc((size_t)n * 8 * 4);
    float* adst1   = (float*)alloc((size_t)n * 8 * 4);
    float* h2      = (float*)alloc((size_t)n * 8 * 4);
    float* asrc2   = (float*)alloc((size_t)n * 4);
    float* adst2   = (float*)alloc((size_t)n * 4);
    int*   counts  = (int*)alloc((size_t)n * 4);
    int*   offsets = (int*)alloc(((size_t)n + 1) * 4);
    int*   csr     = (int*)alloc((size_t)E * 4);
    unsigned int* tmp = (unsigned int*)alloc((size_t)E * 4);
    int*   bucketCounts = (int*)alloc(512 * 4);
    int*   bucketBase   = (int*)alloc(513 * 4);
    int*   bucketCursor = (int*)alloc(512 * 4);
    unsigned short* whiT = (unsigned short*)alloc((size_t)IN_DIM * 64 * 2);
    unsigned short* wloT = (unsigned short*)alloc((size_t)IN_DIM * 64 * 2);

    hipMemsetAsync(bucketCounts, 0, 512 * 4, stream);
    bucket_hist_kernel<<<512, 256, 0, stream>>>(dstv, bucketCounts, E, nbuck);
    w1_split_kernel<<<(IN_DIM * 64 + 255) / 256, 256, 0, stream>>>(W1, whiT, wloT);
    gemm1_kernel<<<(n + 63) / 64, 256, 0, stream>>>(
        x, whiT, wloT, as1, ad1, h1, asrc1, adst1, n);
    bucket_scan_kernel<<<1, 512, 0, stream>>>(bucketCounts, bucketBase, bucketCursor, nbuck);
    coarse_scatter_kernel<<<(E + 256 * K3_EPT - 1) / (256 * K3_EPT), 256, 0, stream>>>(
        srcv, dstv, bucketCursor, tmp, E);
    fine_scatter_kernel<<<nbuck, 256, 0, stream>>>(
        tmp, bucketBase, csr, offsets, counts, n);
    l1_edge_kernel<<<(n + 3) / 4, 256, 0, stream>>>(
        offsets, counts, csr, asrc1, adst1, h1, b1, W2, as2, ad2, h2, asrc2, adst2, n);
    l2_edge_kernel<<<(n + 3) / 4, 256, 0, stream>>>(
        offsets, counts, csr, asrc2, adst2, h2, b2, out, n);
}

// Round 10
// 209.363 us; speedup vs baseline: 1.1269x; 1.0826x over previous
//
#include <hip/hip_runtime.h>
#include <hip/hip_bf16.h>

#define IN_DIM 512
#define HEADS 8
#define HID 8
#define OUT_DIM 7
#define NEG_SLOPE 0.2f

typedef __attribute__((ext_vector_type(8))) short short8b;   // 8 bf16 (4 VGPR)
typedef __attribute__((ext_vector_type(4))) float f32x4;

// ---------------- W1 split prep: W1(f32,[512][64]) -> hi/lo bf16 transposed [64][512]
__global__ __launch_bounds__(256) void w1_split_kernel(
    const float* __restrict__ W1, unsigned short* __restrict__ whiT,
    unsigned short* __restrict__ wloT)
{
    int i = blockIdx.x * 256 + threadIdx.x;   // i = k*64 + c
    if (i >= IN_DIM * 64) return;
    int k = i >> 6, c = i & 63;
    float w = W1[i];
    unsigned u = __float_as_uint(w);
    unsigned hu = u & 0xFFFF0000u;
    float rem = w - __uint_as_float(hu);
    whiT[c * IN_DIM + k] = (unsigned short)(hu >> 16);
    wloT[c * IN_DIM + k] = (unsigned short)(__float_as_uint(rem) >> 16);
}

// ---------------- GEMM1 via split-bf16 MFMA, K-split across 4 waves ----------
// Block = 16 rows; wave w handles k in [w*128,(w+1)*128). LDS-reduce partials.
// acc = xhi*whi + xhi*wlo + xlo*whi  (xlo*wlo dropped, ~2^-16 rel).
__global__ __launch_bounds__(256) void gemm1_kernel(
    const float* __restrict__ x,
    const unsigned short* __restrict__ whiT, const unsigned short* __restrict__ wloT,
    const float* __restrict__ as1, const float* __restrict__ ad1,
    float* __restrict__ h1, float* __restrict__ asrc1, float* __restrict__ adst1,
    int n)
{
    __shared__ float red[4][16][68];   // [wave][row][col], +4 pad -> 2-way banks
    int t = threadIdx.x;
    int wave = t >> 6, l = t & 63;
    int il = l & 15, g = l >> 4;
    int r0 = blockIdx.x * 16;
    int rowA = r0 + il; if (rowA >= n) rowA = n - 1;   // clamp loads; stores guarded
    int kw = wave * 128;
    const float* xp = x + (size_t)rowA * IN_DIM + kw + 8 * g;

    f32x4 acc[4] = {{0.f,0.f,0.f,0.f},{0.f,0.f,0.f,0.f},{0.f,0.f,0.f,0.f},{0.f,0.f,0.f,0.f}};

    #pragma unroll
    for (int k0 = 0; k0 < 128; k0 += 32) {
        float4 a0 = *(const float4*)(xp + k0);
        float4 a1 = *(const float4*)(xp + k0 + 4);
        float av[8] = {a0.x, a0.y, a0.z, a0.w, a1.x, a1.y, a1.z, a1.w};
        short8b Ahi, Alo;
        #pragma unroll
        for (int j = 0; j < 8; ++j) {
            unsigned u = __float_as_uint(av[j]);
            unsigned hu = u & 0xFFFF0000u;
            float rem = av[j] - __uint_as_float(hu);
            Ahi[j] = (short)(hu >> 16);
            Alo[j] = (short)(__float_as_uint(rem) >> 16);
        }
        int bofs = kw + k0 + 8 * g;
        #pragma unroll
        for (int T = 0; T < 4; ++T) {
            short8b Bhi = *(const short8b*)(whiT + ((16 * T + il) * IN_DIM + bofs));
            short8b Blo = *(const short8b*)(wloT + ((16 * T + il) * IN_DIM + bofs));
            acc[T] = __builtin_amdgcn_mfma_f32_16x16x32_bf16(Alo, Bhi, acc[T], 0, 0, 0);
            acc[T] = __builtin_amdgcn_mfma_f32_16x16x32_bf16(Ahi, Blo, acc[T], 0, 0, 0);
            acc[T] = __builtin_amdgcn_mfma_f32_16x16x32_bf16(Ahi, Bhi, acc[T], 0, 0, 0);
        }
    }

    // D layout: col = 16T + il, row = 4g + r. Stash partials in LDS.
    #pragma unroll
    for (int T = 0; T < 4; ++T)
        #pragma unroll
        for (int r = 0; r < 4; ++r)
            red[wave][4 * g + r][16 * T + il] = acc[T][r];
    __syncthreads();

    // Reduce: thread t owns row t>>4, cols (t&15)*4 .. +3.
    int row = t >> 4, c0 = (t & 15) * 4;
    int grow = r0 + row;
    float v0 = red[0][row][c0]     + red[1][row][c0]     + red[2][row][c0]     + red[3][row][c0];
    float v1 = red[0][row][c0 + 1] + red[1][row][c0 + 1] + red[2][row][c0 + 1] + red[3][row][c0 + 1];
    float v2 = red[0][row][c0 + 2] + red[1][row][c0 + 2] + red[2][row][c0 + 2] + red[3][row][c0 + 2];
    float v3 = red[0][row][c0 + 3] + red[1][row][c0 + 3] + red[2][row][c0 + 3] + red[3][row][c0 + 3];
    if (grow < n) {
        *(float4*)(h1 + (size_t)grow * 64 + c0) = make_float4(v0, v1, v2, v3);
        float4 asv = *(const float4*)(as1 + c0);
        float4 adv = *(const float4*)(ad1 + c0);
        float pa = v0 * asv.x + v1 * asv.y + v2 * asv.z + v3 * asv.w;
        float pd = v0 * adv.x + v1 * adv.y + v2 * adv.z + v3 * adv.w;
        pa += __shfl_xor(pa, 1);
        pd += __shfl_xor(pd, 1);
        if ((t & 1) == 0) {
            int head = (t & 15) >> 1;
            asrc1[grow * 8 + head] = pa;
            adst1[grow * 8 + head] = pd;
        }
    }
}

// ---------------- CSR build: bucketed two-stage, 128-node buckets ----------
#define BSHIFT 7
#define BMASK 127
__global__ __launch_bounds__(256) void bucket_hist_kernel(
    const int* __restrict__ dst, int* __restrict__ bucketCounts, int E, int nbuck)
{
    __shared__ int cnt[512];
    int t = threadIdx.x;
    cnt[t] = 0; cnt[t + 256] = 0;
    __syncthreads();
    int i = blockIdx.x * blockDim.x + t;
    int stride = gridDim.x * blockDim.x;
    for (; i < E; i += stride) atomicAdd(&cnt[dst[i] >> BSHIFT], 1);
    __syncthreads();
    if (t < nbuck && cnt[t]) atomicAdd(&bucketCounts[t], cnt[t]);
    int t2 = t + 256;
    if (t2 < nbuck && cnt[t2]) atomicAdd(&bucketCounts[t2], cnt[t2]);
}

__global__ __launch_bounds__(512) void bucket_scan_kernel(
    const int* __restrict__ bucketCounts, int* __restrict__ bucketBase,
    int* __restrict__ bucketCursor, int nbuck)
{
    __shared__ int wsum[8];
    int t = threadIdx.x, lane = t & 63, w = t >> 6;
    int c = (t < nbuck) ? bucketCounts[t] : 0;
    int inc = c;
    #pragma unroll
    for (int d = 1; d < 64; d <<= 1) {
        int u = __shfl_up(inc, d);
        if (lane >= d) inc += u;
    }
    if (lane == 63) wsum[w] = inc;
    __syncthreads();
    if (t == 0) { int run = 0; for (int k = 0; k < 8; ++k) { int tmp = wsum[k]; wsum[k] = run; run += tmp; } }
    __syncthreads();
    int excl = inc - c + wsum[w];
    if (t < nbuck) { bucketBase[t] = excl; bucketCursor[t] = excl; }
    if (t == nbuck) bucketBase[t] = excl;
}

#define K3_EPT 16
__global__ __launch_bounds__(256) void coarse_scatter_kernel(
    const int* __restrict__ src, const int* __restrict__ dst,
    int* __restrict__ bucketCursor, unsigned int* __restrict__ tmp, int E)
{
    __shared__ int cnt[512];
    __shared__ int gbase[512];
    int t = threadIdx.x;
    cnt[t] = 0; cnt[t + 256] = 0;
    __syncthreads();
    int base = blockIdx.x * (256 * K3_EPT);
    unsigned int pk[K3_EPT];
    unsigned int meta[K3_EPT];
    #pragma unroll
    for (int j = 0; j < K3_EPT; ++j) {
        int i = base + t + j * 256;
        if (i < E) {
            int d = dst[i], s = src[i];
            int b = d >> BSHIFT;
            pk[j] = ((unsigned)s << 16) | (unsigned)(d & BMASK);
            int r = atomicAdd(&cnt[b], 1);
            meta[j] = ((unsigned)r << 9) | (unsigned)b;
        } else {
            meta[j] = 0xFFFFFFFFu; pk[j] = 0;
        }
    }
    __syncthreads();
    if (cnt[t] > 0) gbase[t] = atomicAdd(&bucketCursor[t], cnt[t]);
    int t2 = t + 256;
    if (cnt[t2] > 0) gbase[t2] = atomicAdd(&bucketCursor[t2], cnt[t2]);
    __syncthreads();
    #pragma unroll
    for (int j = 0; j < K3_EPT; ++j) {
        if (meta[j] != 0xFFFFFFFFu) {
            int b = meta[j] & 511;
            int r = meta[j] >> 9;
            tmp[gbase[b] + r] = pk[j];
        }
    }
}

__global__ __launch_bounds__(256) void fine_scatter_kernel(
    const unsigned int* __restrict__ tmp, const int* __restrict__ bucketBase,
    int* __restrict__ csr, int* __restrict__ offsets, int* __restrict__ counts, int n)
{
    __shared__ int cnt[128];
    __shared__ int cur[128];
    __shared__ int wsum[2];
    int b = blockIdx.x;
    int t = threadIdx.x, lane = t & 63, w = t >> 6;
    int beg = bucketBase[b], end = bucketBase[b + 1];
    if (t < 128) cnt[t] = 0;
    __syncthreads();
    for (int i = beg + t; i < end; i += 256)
        atomicAdd(&cnt[tmp[i] & BMASK], 1);
    __syncthreads();
    if (t < 128) {
        int c = cnt[t];
        int inc = c;
        #pragma unroll
        for (int d = 1; d < 64; d <<= 1) {
            int u = __shfl_up(inc, d);
            if (lane >= d) inc += u;
        }
        if (lane == 63) wsum[w] = inc;
        __syncthreads();
        if (t == 0) { int r0_ = wsum[0]; wsum[0] = 0; wsum[1] = r0_; }
        __syncthreads();
        int excl = inc - c + wsum[w];
        int node = b * 128 + t;
        if (node < n) { offsets[node] = beg + excl; counts[node] = c; }
        cur[t] = excl;
    } else {
        __syncthreads(); __syncthreads();
    }
    __syncthreads();
    for (int i = beg + t; i < end; i += 256) {
        unsigned int p = tmp[i];
        int r = atomicAdd(&cur[p & BMASK], 1);
        csr[beg + r] = (int)(p >> 16);
    }
}

// ---------------- Layer-1 edge kernel: single-pass (no max) ----------------
__global__ __launch_bounds__(256) void l1_edge_kernel(
    const int* __restrict__ offsets, const int* __restrict__ counts,
    const int* __restrict__ csr,
    const float* __restrict__ asrc1, const float* __restrict__ adst1,
    const float* __restrict__ h1, const float* __restrict__ b1,
    const float* __restrict__ W2, const float* __restrict__ as2,
    const float* __restrict__ ad2,
    float* __restrict__ h2, float* __restrict__ asrc2, float* __restrict__ adst2,
    int n)
{
    __shared__ float w2t[8][64];
    __shared__ float s_as2[8], s_ad2[8], s_b1[64];
    int t = threadIdx.x;
    if (t < 64) {
        #pragma unroll
        for (int j = 0; j < OUT_DIM; ++j) w2t[j][t] = W2[t * OUT_DIM + j];
        s_b1[t] = b1[t];
        if (t < OUT_DIM) { s_as2[t] = as2[t]; s_ad2[t] = ad2[t]; }
    }
    __syncthreads();

    int lane = t & 63;
    int node = blockIdx.x * 4 + (t >> 6);
    if (node >= n) return;
    int beg = offsets[node];
    int deg = counts[node];
    int q = lane >> 4;
    int il = lane & 15;
    int c0 = il * 4;
    int head = il >> 1;
    float adv = adst1[node * 8 + head];

    float4 acc = make_float4(0.f, 0.f, 0.f, 0.f);
    float ssum = 0.f;
    if (q == 0) {
        float e = asrc1[node * 8 + head] + adv;
        e = e > 0.f ? e : NEG_SLOPE * e;
        float p = __expf(e);
        float4 hv = *(const float4*)(h1 + (size_t)node * 64 + c0);
        acc.x = p * hv.x; acc.y = p * hv.y; acc.z = p * hv.z; acc.w = p * hv.w;
        ssum = p;
    }
    int j = q;
    for (; j + 4 < deg; j += 8) {
        int s0 = csr[beg + j], s1 = csr[beg + j + 4];
        float a0 = asrc1[s0 * 8 + head], a1 = asrc1[s1 * 8 + head];
        float4 g0 = *(const float4*)(h1 + (size_t)s0 * 64 + c0);
        float4 g1 = *(const float4*)(h1 + (size_t)s1 * 64 + c0);
        float e0 = a0 + adv; e0 = e0 > 0.f ? e0 : NEG_SLOPE * e0;
        float e1 = a1 + adv; e1 = e1 > 0.f ? e1 : NEG_SLOPE * e1;
        float p0 = __expf(e0), p1 = __expf(e1);
        acc.x = fmaf(p0, g0.x, acc.x); acc.y = fmaf(p0, g0.y, acc.y);
        acc.z = fmaf(p0, g0.z, acc.z); acc.w = fmaf(p0, g0.w, acc.w);
        acc.x = fmaf(p1, g1.x, acc.x); acc.y = fmaf(p1, g1.y, acc.y);
        acc.z = fmaf(p1, g1.z, acc.z); acc.w = fmaf(p1, g1.w, acc.w);
        ssum += p0 + p1;
    }
    for (; j < deg; j += 4) {
        int sn = csr[beg + j];
        float a = asrc1[sn * 8 + head];
        float4 g = *(const float4*)(h1 + (size_t)sn * 64 + c0);
        float e = a + adv; e = e > 0.f ? e : NEG_SLOPE * e;
        float p = __expf(e);
        acc.x = fmaf(p, g.x, acc.x); acc.y = fmaf(p, g.y, acc.y);
        acc.z = fmaf(p, g.z, acc.z); acc.w = fmaf(p, g.w, acc.w);
        ssum += p;
    }
    acc.x += __shfl_xor(acc.x, 16); acc.x += __shfl_xor(acc.x, 32);
    acc.y += __shfl_xor(acc.y, 16); acc.y += __shfl_xor(acc.y, 32);
    acc.z += __shfl_xor(acc.z, 16); acc.z += __shfl_xor(acc.z, 32);
    acc.w += __shfl_xor(acc.w, 16); acc.w += __shfl_xor(acc.w, 32);
    ssum  += __shfl_xor(ssum, 16);  ssum  += __shfl_xor(ssum, 32);
    float inv = 1.f / fmaxf(ssum, 1e-16f);

    float4 bv = *(const float4*)(&s_b1[c0]);
    float v0 = acc.x * inv + bv.x;
    float v1 = acc.y * inv + bv.y;
    float v2 = acc.z * inv + bv.z;
    float v3 = acc.w * inv + bv.w;
    v0 = v0 > 0.f ? v0 : __expf(v0) - 1.f;
    v1 = v1 > 0.f ? v1 : __expf(v1) - 1.f;
    v2 = v2 > 0.f ? v2 : __expf(v2) - 1.f;
    v3 = v3 > 0.f ? v3 : __expf(v3) - 1.f;

    float hj[OUT_DIM];
    #pragma unroll
    for (int jj = 0; jj < OUT_DIM; ++jj) {
        float4 wv = *(const float4*)(&w2t[jj][c0]);
        float p = v0 * wv.x + v1 * wv.y + v2 * wv.z + v3 * wv.w;
        p += __shfl_xor(p, 1);
        p += __shfl_xor(p, 2);
        p += __shfl_xor(p, 4);
        p += __shfl_xor(p, 8);
        hj[jj] = p;
    }
    float a_s = 0.f, a_d = 0.f;
    #pragma unroll
    for (int jj = 0; jj < OUT_DIM; ++jj) { a_s += hj[jj] * s_as2[jj]; a_d += hj[jj] * s_ad2[jj]; }
    if (lane < 8) h2[node * 8 + lane] = (lane < OUT_DIM) ? hj[lane] : 0.f;
    if (lane == 0) { asrc2[node] = a_s; adst2[node] = a_d; }
}

// ---------------- Layer-2 edge kernel: single-pass -> final logits --------
__global__ __launch_bounds__(256) void l2_edge_kernel(
    const int* __restrict__ offsets, const int* __restrict__ counts,
    const int* __restrict__ csr,
    const float* __restrict__ asrc2, const float* __restrict__ adst2,
    const float* __restrict__ h2, const float* __restrict__ b2,
    float* __restrict__ out, int n)
{
    int t = threadIdx.x, lane = t & 63;
    int node = blockIdx.x * 4 + (t >> 6);
    if (node >= n) return;
    int beg = offsets[node];
    int deg = counts[node];
    float adv = adst2[node];

    int c = lane & 7, slot = lane >> 3;
    float acc = 0.f, ssum = 0.f;
    if (slot == 0) {
        float e = asrc2[node] + adv;
        e = e > 0.f ? e : NEG_SLOPE * e;
        float p = __expf(e);
        acc = p * h2[node * 8 + c];
        ssum = p;
    }
    int j = slot;
    for (; j + 8 < deg; j += 16) {
        int s0 = csr[beg + j], s1 = csr[beg + j + 8];
        float a0 = asrc2[s0], a1 = asrc2[s1];
        float g0 = h2[s0 * 8 + c], g1 = h2[s1 * 8 + c];
        float e0 = a0 + adv; e0 = e0 > 0.f ? e0 : NEG_SLOPE * e0;
        float e1 = a1 + adv; e1 = e1 > 0.f ? e1 : NEG_SLOPE * e1;
        float p0 = __expf(e0), p1 = __expf(e1);
        acc = fmaf(p0, g0, acc); acc = fmaf(p1, g1, acc);
        ssum += p0 + p1;
    }
    for (; j < deg; j += 8) {
        int sn = csr[beg + j];
        float e = asrc2[sn] + adv;
        e = e > 0.f ? e : NEG_SLOPE * e;
        float p = __expf(e);
        acc = fmaf(p, h2[sn * 8 + c], acc);
        ssum += p;
    }
    acc  += __shfl_xor(acc, 8);  acc  += __shfl_xor(acc, 16);  acc  += __shfl_xor(acc, 32);
    ssum += __shfl_xor(ssum, 8); ssum += __shfl_xor(ssum, 16); ssum += __shfl_xor(ssum, 32);
    float inv = 1.f / fmaxf(ssum, 1e-16f);
    if (lane < OUT_DIM) out[(size_t)node * OUT_DIM + lane] = acc * inv + b2[lane];
}

// ---------------- launch ----------------
static inline size_t rup256(size_t x) { return (x + 255) & ~(size_t)255; }

extern "C" void kernel_launch(void* const* d_in, const int* in_sizes, int n_in,
                              void* d_out, int out_size, void* d_ws, size_t ws_size,
                              hipStream_t stream)
{
    int n = in_sizes[0] / IN_DIM;       // 50000
    int E = in_sizes[1] / 2;            // 1600000
    int nbuck = (n + BMASK) >> BSHIFT;  // 391

    const float* x   = (const float*)d_in[0];
    const int*   ei  = (const int*)d_in[1];
    const int*   srcv = ei;
    const int*   dstv = ei + E;
    const float* W1  = (const float*)d_in[2];
    const float* as1 = (const float*)d_in[3];
    const float* ad1 = (const float*)d_in[4];
    const float* b1  = (const float*)d_in[5];
    const float* W2  = (const float*)d_in[6];
    const float* as2 = (const float*)d_in[7];
    const float* ad2 = (const float*)d_in[8];
    const float* b2  = (const float*)d_in[9];
    float* out = (float*)d_out;

    char* p = (char*)d_ws;
    auto alloc = [&](size_t bytes) { char* q = p; p += rup256(bytes); return (void*)q; };
    float* h1      = (float*)alloc((size_t)n * 64 * 4);
    float* asrc1   = (float*)alloc((size_t)n * 8 * 4);
    float* adst1   = (float*)alloc((size_t)n * 8 * 4);
    float* h2      = (float*)alloc((size_t)n * 8 * 4);
    float* asrc2   = (float*)alloc((size_t)n * 4);
    float* adst2   = (float*)alloc((size_t)n * 4);
    int*   counts  = (int*)alloc((size_t)n * 4);
    int*   offsets = (int*)alloc(((size_t)n + 1) * 4);
    int*   csr     = (int*)alloc((size_t)E * 4);
    unsigned int* tmp = (unsigned int*)alloc((size_t)E * 4);
    int*   bucketCounts = (int*)alloc(512 * 4);
    int*   bucketBase   = (int*)alloc(513 * 4);
    int*   bucketCursor = (int*)alloc(512 * 4);
    unsigned short* whiT = (unsigned short*)alloc((size_t)IN_DIM * 64 * 2);
    unsigned short* wloT = (unsigned short*)alloc((size_t)IN_DIM * 64 * 2);

    hipMemsetAsync(bucketCounts, 0, 512 * 4, stream);
    bucket_hist_kernel<<<512, 256, 0, stream>>>(dstv, bucketCounts, E, nbuck);
    w1_split_kernel<<<(IN_DIM * 64 + 255) / 256, 256, 0, stream>>>(W1, whiT, wloT);
    gemm1_kernel<<<(n + 15) / 16, 256, 0, stream>>>(
        x, whiT, wloT, as1, ad1, h1, asrc1, adst1, n);
    bucket_scan_kernel<<<1, 512, 0, stream>>>(bucketCounts, bucketBase, bucketCursor, nbuck);
    coarse_scatter_kernel<<<(E + 256 * K3_EPT - 1) / (256 * K3_EPT), 256, 0, stream>>>(
        srcv, dstv, bucketCursor, tmp, E);
    fine_scatter_kernel<<<nbuck, 256, 0, stream>>>(
        tmp, bucketBase, csr, offsets, counts, n);
    l1_edge_kernel<<<(n + 3) / 4, 256, 0, stream>>>(
        offsets, counts, csr, asrc1, adst1, h1, b1, W2, as2, ad2, h2, asrc2, adst2, n);
    l2_edge_kernel<<<(n + 3) / 4, 256, 0, stream>>>(
        offsets, counts, csr, asrc2, adst2, h2, b2, out, n);
}

// Round 11
// 209.052 us; speedup vs baseline: 1.1286x; 1.0015x over previous
//
#include <hip/hip_runtime.h>
#include <hip/hip_bf16.h>

#define IN_DIM 512
#define HEADS 8
#define HID 8
#define OUT_DIM 7
#define NEG_SLOPE 0.2f

typedef __attribute__((ext_vector_type(8))) short short8b;   // 8 bf16 (4 VGPR)
typedef __attribute__((ext_vector_type(4))) float f32x4;

// ---------------- W1 split prep: W1(f32,[512][64]) -> hi/lo bf16 transposed [64][512]
__global__ __launch_bounds__(256) void w1_split_kernel(
    const float* __restrict__ W1, unsigned short* __restrict__ whiT,
    unsigned short* __restrict__ wloT)
{
    int i = blockIdx.x * 256 + threadIdx.x;   // i = k*64 + c
    if (i >= IN_DIM * 64) return;
    int k = i >> 6, c = i & 63;
    float w = W1[i];
    unsigned u = __float_as_uint(w);
    unsigned hu = u & 0xFFFF0000u;
    float rem = w - __uint_as_float(hu);
    whiT[c * IN_DIM + k] = (unsigned short)(hu >> 16);
    wloT[c * IN_DIM + k] = (unsigned short)(__float_as_uint(rem) >> 16);
}

// ---------------- GEMM1 via split-bf16 MFMA, K-split across 4 waves ----------
// Block = 16 rows; wave w handles k in [w*128,(w+1)*128). LDS-reduce partials.
// All 8 x-loads hoisted to the top (8 KB/wave in flight) to hide HBM latency.
// acc = xhi*whi + xhi*wlo + xlo*whi  (xlo*wlo dropped, ~2^-16 rel).
__global__ __launch_bounds__(256) void gemm1_kernel(
    const float* __restrict__ x,
    const unsigned short* __restrict__ whiT, const unsigned short* __restrict__ wloT,
    const float* __restrict__ as1, const float* __restrict__ ad1,
    float* __restrict__ h1, float* __restrict__ asrc1, float* __restrict__ adst1,
    int n)
{
    __shared__ float red[4][16][68];   // [wave][row][col], +4 pad -> 2-way banks
    int t = threadIdx.x;
    int wave = t >> 6, l = t & 63;
    int il = l & 15, g = l >> 4;
    int r0 = blockIdx.x * 16;
    int rowA = r0 + il; if (rowA >= n) rowA = n - 1;   // clamp loads; stores guarded
    int kw = wave * 128;
    const float* xp = x + (size_t)rowA * IN_DIM + kw + 8 * g;

    // ---- issue ALL x loads up front: 8 float4 VMEM in flight per wave ----
    float4 xl[8];
    #pragma unroll
    for (int it = 0; it < 4; ++it) {
        xl[2 * it]     = *(const float4*)(xp + 32 * it);
        xl[2 * it + 1] = *(const float4*)(xp + 32 * it + 4);
    }

    f32x4 acc[4] = {{0.f,0.f,0.f,0.f},{0.f,0.f,0.f,0.f},{0.f,0.f,0.f,0.f},{0.f,0.f,0.f,0.f}};

    #pragma unroll
    for (int it = 0; it < 4; ++it) {
        float av[8] = {xl[2*it].x, xl[2*it].y, xl[2*it].z, xl[2*it].w,
                       xl[2*it+1].x, xl[2*it+1].y, xl[2*it+1].z, xl[2*it+1].w};
        short8b Ahi, Alo;
        #pragma unroll
        for (int j = 0; j < 8; ++j) {
            unsigned u = __float_as_uint(av[j]);
            unsigned hu = u & 0xFFFF0000u;
            float rem = av[j] - __uint_as_float(hu);
            Ahi[j] = (short)(hu >> 16);
            Alo[j] = (short)(__float_as_uint(rem) >> 16);
        }
        int bofs = kw + 32 * it + 8 * g;
        // hoist all 8 B-frag loads so L2 latency overlaps across T
        short8b Bh[4], Bl[4];
        #pragma unroll
        for (int T = 0; T < 4; ++T) {
            Bh[T] = *(const short8b*)(whiT + ((16 * T + il) * IN_DIM + bofs));
            Bl[T] = *(const short8b*)(wloT + ((16 * T + il) * IN_DIM + bofs));
        }
        #pragma unroll
        for (int T = 0; T < 4; ++T) {
            acc[T] = __builtin_amdgcn_mfma_f32_16x16x32_bf16(Alo, Bh[T], acc[T], 0, 0, 0);
            acc[T] = __builtin_amdgcn_mfma_f32_16x16x32_bf16(Ahi, Bl[T], acc[T], 0, 0, 0);
            acc[T] = __builtin_amdgcn_mfma_f32_16x16x32_bf16(Ahi, Bh[T], acc[T], 0, 0, 0);
        }
    }

    // D layout: col = 16T + il, row = 4g + r. Stash partials in LDS.
    #pragma unroll
    for (int T = 0; T < 4; ++T)
        #pragma unroll
        for (int r = 0; r < 4; ++r)
            red[wave][4 * g + r][16 * T + il] = acc[T][r];
    __syncthreads();

    // Reduce: thread t owns row t>>4, cols (t&15)*4 .. +3.
    int row = t >> 4, c0 = (t & 15) * 4;
    int grow = r0 + row;
    float v0 = red[0][row][c0]     + red[1][row][c0]     + red[2][row][c0]     + red[3][row][c0];
    float v1 = red[0][row][c0 + 1] + red[1][row][c0 + 1] + red[2][row][c0 + 1] + red[3][row][c0 + 1];
    float v2 = red[0][row][c0 + 2] + red[1][row][c0 + 2] + red[2][row][c0 + 2] + red[3][row][c0 + 2];
    float v3 = red[0][row][c0 + 3] + red[1][row][c0 + 3] + red[2][row][c0 + 3] + red[3][row][c0 + 3];
    if (grow < n) {
        *(float4*)(h1 + (size_t)grow * 64 + c0) = make_float4(v0, v1, v2, v3);
        float4 asv = *(const float4*)(as1 + c0);
        float4 adv = *(const float4*)(ad1 + c0);
        float pa = v0 * asv.x + v1 * asv.y + v2 * asv.z + v3 * asv.w;
        float pd = v0 * adv.x + v1 * adv.y + v2 * adv.z + v3 * adv.w;
        pa += __shfl_xor(pa, 1);
        pd += __shfl_xor(pd, 1);
        if ((t & 1) == 0) {
            int head = (t & 15) >> 1;
            asrc1[grow * 8 + head] = pa;
            adst1[grow * 8 + head] = pd;
        }
    }
}

// ---------------- CSR build: bucketed two-stage, 128-node buckets ----------
#define BSHIFT 7
#define BMASK 127
__global__ __launch_bounds__(256) void bucket_hist_kernel(
    const int* __restrict__ dst, int* __restrict__ bucketCounts, int E, int nbuck)
{
    __shared__ int cnt[512];
    int t = threadIdx.x;
    cnt[t] = 0; cnt[t + 256] = 0;
    __syncthreads();
    int i = blockIdx.x * blockDim.x + t;
    int stride = gridDim.x * blockDim.x;
    for (; i < E; i += stride) atomicAdd(&cnt[dst[i] >> BSHIFT], 1);
    __syncthreads();
    if (t < nbuck && cnt[t]) atomicAdd(&bucketCounts[t], cnt[t]);
    int t2 = t + 256;
    if (t2 < nbuck && cnt[t2]) atomicAdd(&bucketCounts[t2], cnt[t2]);
}

__global__ __launch_bounds__(512) void bucket_scan_kernel(
    const int* __restrict__ bucketCounts, int* __restrict__ bucketBase,
    int* __restrict__ bucketCursor, int nbuck)
{
    __shared__ int wsum[8];
    int t = threadIdx.x, lane = t & 63, w = t >> 6;
    int c = (t < nbuck) ? bucketCounts[t] : 0;
    int inc = c;
    #pragma unroll
    for (int d = 1; d < 64; d <<= 1) {
        int u = __shfl_up(inc, d);
        if (lane >= d) inc += u;
    }
    if (lane == 63) wsum[w] = inc;
    __syncthreads();
    if (t == 0) { int run = 0; for (int k = 0; k < 8; ++k) { int tmp = wsum[k]; wsum[k] = run; run += tmp; } }
    __syncthreads();
    int excl = inc - c + wsum[w];
    if (t < nbuck) { bucketBase[t] = excl; bucketCursor[t] = excl; }
    if (t == nbuck) bucketBase[t] = excl;
}

#define K3_EPT 16
__global__ __launch_bounds__(256) void coarse_scatter_kernel(
    const int* __restrict__ src, const int* __restrict__ dst,
    int* __restrict__ bucketCursor, unsigned int* __restrict__ tmp, int E)
{
    __shared__ int cnt[512];
    __shared__ int gbase[512];
    int t = threadIdx.x;
    cnt[t] = 0; cnt[t + 256] = 0;
    __syncthreads();
    int base = blockIdx.x * (256 * K3_EPT);
    unsigned int pk[K3_EPT];
    unsigned int meta[K3_EPT];
    #pragma unroll
    for (int j = 0; j < K3_EPT; ++j) {
        int i = base + t + j * 256;
        if (i < E) {
            int d = dst[i], s = src[i];
            int b = d >> BSHIFT;
            pk[j] = ((unsigned)s << 16) | (unsigned)(d & BMASK);
            int r = atomicAdd(&cnt[b], 1);
            meta[j] = ((unsigned)r << 9) | (unsigned)b;
        } else {
            meta[j] = 0xFFFFFFFFu; pk[j] = 0;
        }
    }
    __syncthreads();
    if (cnt[t] > 0) gbase[t] = atomicAdd(&bucketCursor[t], cnt[t]);
    int t2 = t + 256;
    if (cnt[t2] > 0) gbase[t2] = atomicAdd(&bucketCursor[t2], cnt[t2]);
    __syncthreads();
    #pragma unroll
    for (int j = 0; j < K3_EPT; ++j) {
        if (meta[j] != 0xFFFFFFFFu) {
            int b = meta[j] & 511;
            int r = meta[j] >> 9;
            tmp[gbase[b] + r] = pk[j];
        }
    }
}

__global__ __launch_bounds__(256) void fine_scatter_kernel(
    const unsigned int* __restrict__ tmp, const int* __restrict__ bucketBase,
    int* __restrict__ csr, int* __restrict__ offsets, int* __restrict__ counts, int n)
{
    __shared__ int cnt[128];
    __shared__ int cur[128];
    __shared__ int wsum[2];
    int b = blockIdx.x;
    int t = threadIdx.x, lane = t & 63, w = t >> 6;
    int beg = bucketBase[b], end = bucketBase[b + 1];
    if (t < 128) cnt[t] = 0;
    __syncthreads();
    for (int i = beg + t; i < end; i += 256)
        atomicAdd(&cnt[tmp[i] & BMASK], 1);
    __syncthreads();
    if (t < 128) {
        int c = cnt[t];
        int inc = c;
        #pragma unroll
        for (int d = 1; d < 64; d <<= 1) {
            int u = __shfl_up(inc, d);
            if (lane >= d) inc += u;
        }
        if (lane == 63) wsum[w] = inc;
        __syncthreads();
        if (t == 0) { int r0_ = wsum[0]; wsum[0] = 0; wsum[1] = r0_; }
        __syncthreads();
        int excl = inc - c + wsum[w];
        int node = b * 128 + t;
        if (node < n) { offsets[node] = beg + excl; counts[node] = c; }
        cur[t] = excl;
    } else {
        __syncthreads(); __syncthreads();
    }
    __syncthreads();
    for (int i = beg + t; i < end; i += 256) {
        unsigned int p = tmp[i];
        int r = atomicAdd(&cur[p & BMASK], 1);
        csr[beg + r] = (int)(p >> 16);
    }
}

// ---------------- Layer-1 edge kernel: single-pass (no max) ----------------
__global__ __launch_bounds__(256) void l1_edge_kernel(
    const int* __restrict__ offsets, const int* __restrict__ counts,
    const int* __restrict__ csr,
    const float* __restrict__ asrc1, const float* __restrict__ adst1,
    const float* __restrict__ h1, const float* __restrict__ b1,
    const float* __restrict__ W2, const float* __restrict__ as2,
    const float* __restrict__ ad2,
    float* __restrict__ h2, float* __restrict__ asrc2, float* __restrict__ adst2,
    int n)
{
    __shared__ float w2t[8][64];
    __shared__ float s_as2[8], s_ad2[8], s_b1[64];
    int t = threadIdx.x;
    if (t < 64) {
        #pragma unroll
        for (int j = 0; j < OUT_DIM; ++j) w2t[j][t] = W2[t * OUT_DIM + j];
        s_b1[t] = b1[t];
        if (t < OUT_DIM) { s_as2[t] = as2[t]; s_ad2[t] = ad2[t]; }
    }
    __syncthreads();

    int lane = t & 63;
    int node = blockIdx.x * 4 + (t >> 6);
    if (node >= n) return;
    int beg = offsets[node];
    int deg = counts[node];
    int q = lane >> 4;
    int il = lane & 15;
    int c0 = il * 4;
    int head = il >> 1;
    float adv = adst1[node * 8 + head];

    float4 acc = make_float4(0.f, 0.f, 0.f, 0.f);
    float ssum = 0.f;
    if (q == 0) {
        float e = asrc1[node * 8 + head] + adv;
        e = e > 0.f ? e : NEG_SLOPE * e;
        float p = __expf(e);
        float4 hv = *(const float4*)(h1 + (size_t)node * 64 + c0);
        acc.x = p * hv.x; acc.y = p * hv.y; acc.z = p * hv.z; acc.w = p * hv.w;
        ssum = p;
    }
    int j = q;
    for (; j + 4 < deg; j += 8) {
        int s0 = csr[beg + j], s1 = csr[beg + j + 4];
        float a0 = asrc1[s0 * 8 + head], a1 = asrc1[s1 * 8 + head];
        float4 g0 = *(const float4*)(h1 + (size_t)s0 * 64 + c0);
        float4 g1 = *(const float4*)(h1 + (size_t)s1 * 64 + c0);
        float e0 = a0 + adv; e0 = e0 > 0.f ? e0 : NEG_SLOPE * e0;
        float e1 = a1 + adv; e1 = e1 > 0.f ? e1 : NEG_SLOPE * e1;
        float p0 = __expf(e0), p1 = __expf(e1);
        acc.x = fmaf(p0, g0.x, acc.x); acc.y = fmaf(p0, g0.y, acc.y);
        acc.z = fmaf(p0, g0.z, acc.z); acc.w = fmaf(p0, g0.w, acc.w);
        acc.x = fmaf(p1, g1.x, acc.x); acc.y = fmaf(p1, g1.y, acc.y);
        acc.z = fmaf(p1, g1.z, acc.z); acc.w = fmaf(p1, g1.w, acc.w);
        ssum += p0 + p1;
    }
    for (; j < deg; j += 4) {
        int sn = csr[beg + j];
        float a = asrc1[sn * 8 + head];
        float4 g = *(const float4*)(h1 + (size_t)sn * 64 + c0);
        float e = a + adv; e = e > 0.f ? e : NEG_SLOPE * e;
        float p = __expf(e);
        acc.x = fmaf(p, g.x, acc.x); acc.y = fmaf(p, g.y, acc.y);
        acc.z = fmaf(p, g.z, acc.z); acc.w = fmaf(p, g.w, acc.w);
        ssum += p;
    }
    acc.x += __shfl_xor(acc.x, 16); acc.x += __shfl_xor(acc.x, 32);
    acc.y += __shfl_xor(acc.y, 16); acc.y += __shfl_xor(acc.y, 32);
    acc.z += __shfl_xor(acc.z, 16); acc.z += __shfl_xor(acc.z, 32);
    acc.w += __shfl_xor(acc.w, 16); acc.w += __shfl_xor(acc.w, 32);
    ssum  += __shfl_xor(ssum, 16);  ssum  += __shfl_xor(ssum, 32);
    float inv = 1.f / fmaxf(ssum, 1e-16f);

    float4 bv = *(const float4*)(&s_b1[c0]);
    float v0 = acc.x * inv + bv.x;
    float v1 = acc.y * inv + bv.y;
    float v2 = acc.z * inv + bv.z;
    float v3 = acc.w * inv + bv.w;
    v0 = v0 > 0.f ? v0 : __expf(v0) - 1.f;
    v1 = v1 > 0.f ? v1 : __expf(v1) - 1.f;
    v2 = v2 > 0.f ? v2 : __expf(v2) - 1.f;
    v3 = v3 > 0.f ? v3 : __expf(v3) - 1.f;

    float hj[OUT_DIM];
    #pragma unroll
    for (int jj = 0; jj < OUT_DIM; ++jj) {
        float4 wv = *(const float4*)(&w2t[jj][c0]);
        float p = v0 * wv.x + v1 * wv.y + v2 * wv.z + v3 * wv.w;
        p += __shfl_xor(p, 1);
        p += __shfl_xor(p, 2);
        p += __shfl_xor(p, 4);
        p += __shfl_xor(p, 8);
        hj[jj] = p;
    }
    float a_s = 0.f, a_d = 0.f;
    #pragma unroll
    for (int jj = 0; jj < OUT_DIM; ++jj) { a_s += hj[jj] * s_as2[jj]; a_d += hj[jj] * s_ad2[jj]; }
    if (lane < 8) h2[node * 8 + lane] = (lane < OUT_DIM) ? hj[lane] : 0.f;
    if (lane == 0) { asrc2[node] = a_s; adst2[node] = a_d; }
}

// ---------------- Layer-2 edge kernel: single-pass -> final logits --------
__global__ __launch_bounds__(256) void l2_edge_kernel(
    const int* __restrict__ offsets, const int* __restrict__ counts,
    const int* __restrict__ csr,
    const float* __restrict__ asrc2, const float* __restrict__ adst2,
    const float* __restrict__ h2, const float* __restrict__ b2,
    float* __restrict__ out, int n)
{
    int t = threadIdx.x, lane = t & 63;
    int node = blockIdx.x * 4 + (t >> 6);
    if (node >= n) return;
    int beg = offsets[node];
    int deg = counts[node];
    float adv = adst2[node];

    int c = lane & 7, slot = lane >> 3;
    float acc = 0.f, ssum = 0.f;
    if (slot == 0) {
        float e = asrc2[node] + adv;
        e = e > 0.f ? e : NEG_SLOPE * e;
        float p = __expf(e);
        acc = p * h2[node * 8 + c];
        ssum = p;
    }
    int j = slot;
    for (; j + 8 < deg; j += 16) {
        int s0 = csr[beg + j], s1 = csr[beg + j + 8];
        float a0 = asrc2[s0], a1 = asrc2[s1];
        float g0 = h2[s0 * 8 + c], g1 = h2[s1 * 8 + c];
        float e0 = a0 + adv; e0 = e0 > 0.f ? e0 : NEG_SLOPE * e0;
        float e1 = a1 + adv; e1 = e1 > 0.f ? e1 : NEG_SLOPE * e1;
        float p0 = __expf(e0), p1 = __expf(e1);
        acc = fmaf(p0, g0, acc); acc = fmaf(p1, g1, acc);
        ssum += p0 + p1;
    }
    for (; j < deg; j += 8) {
        int sn = csr[beg + j];
        float e = asrc2[sn] + adv;
        e = e > 0.f ? e : NEG_SLOPE * e;
        float p = __expf(e);
        acc = fmaf(p, h2[sn * 8 + c], acc);
        ssum += p;
    }
    acc  += __shfl_xor(acc, 8);  acc  += __shfl_xor(acc, 16);  acc  += __shfl_xor(acc, 32);
    ssum += __shfl_xor(ssum, 8); ssum += __shfl_xor(ssum, 16); ssum += __shfl_xor(ssum, 32);
    float inv = 1.f / fmaxf(ssum, 1e-16f);
    if (lane < OUT_DIM) out[(size_t)node * OUT_DIM + lane] = acc * inv + b2[lane];
}

// ---------------- launch ----------------
static inline size_t rup256(size_t x) { return (x + 255) & ~(size_t)255; }

extern "C" void kernel_launch(void* const* d_in, const int* in_sizes, int n_in,
                              void* d_out, int out_size, void* d_ws, size_t ws_size,
                              hipStream_t stream)
{
    int n = in_sizes[0] / IN_DIM;       // 50000
    int E = in_sizes[1] / 2;            // 1600000
    int nbuck = (n + BMASK) >> BSHIFT;  // 391

    const float* x   = (const float*)d_in[0];
    const int*   ei  = (const int*)d_in[1];
    const int*   srcv = ei;
    const int*   dstv = ei + E;
    const float* W1  = (const float*)d_in[2];
    const float* as1 = (const float*)d_in[3];
    const float* ad1 = (const float*)d_in[4];
    const float* b1  = (const float*)d_in[5];
    const float* W2  = (const float*)d_in[6];
    const float* as2 = (const float*)d_in[7];
    const float* ad2 = (const float*)d_in[8];
    const float* b2  = (const float*)d_in[9];
    float* out = (float*)d_out;

    char* p = (char*)d_ws;
    auto alloc = [&](size_t bytes) { char* q = p; p += rup256(bytes); return (void*)q; };
    float* h1      = (float*)alloc((size_t)n * 64 * 4);
    float* asrc1   = (float*)alloc((size_t)n * 8 * 4);
    float* adst1   = (float*)alloc((size_t)n * 8 * 4);
    float* h2      = (float*)alloc((size_t)n * 8 * 4);
    float* asrc2   = (float*)alloc((size_t)n * 4);
    float* adst2   = (float*)alloc((size_t)n * 4);
    int*   counts  = (int*)alloc((size_t)n * 4);
    int*   offsets = (int*)alloc(((size_t)n + 1) * 4);
    int*   csr     = (int*)alloc((size_t)E * 4);
    unsigned int* tmp = (unsigned int*)alloc((size_t)E * 4);
    int*   bucketCounts = (int*)alloc(512 * 4);
    int*   bucketBase   = (int*)alloc(513 * 4);
    int*   bucketCursor = (int*)alloc(512 * 4);
    unsigned short* whiT = (unsigned short*)alloc((size_t)IN_DIM * 64 * 2);
    unsigned short* wloT = (unsigned short*)alloc((size_t)IN_DIM * 64 * 2);

    hipMemsetAsync(bucketCounts, 0, 512 * 4, stream);
    bucket_hist_kernel<<<512, 256, 0, stream>>>(dstv, bucketCounts, E, nbuck);
    w1_split_kernel<<<(IN_DIM * 64 + 255) / 256, 256, 0, stream>>>(W1, whiT, wloT);
    gemm1_kernel<<<(n + 15) / 16, 256, 0, stream>>>(
        x, whiT, wloT, as1, ad1, h1, asrc1, adst1, n);
    bucket_scan_kernel<<<1, 512, 0, stream>>>(bucketCounts, bucketBase, bucketCursor, nbuck);
    coarse_scatter_kernel<<<(E + 256 * K3_EPT - 1) / (256 * K3_EPT), 256, 0, stream>>>(
        srcv, dstv, bucketCursor, tmp, E);
    fine_scatter_kernel<<<nbuck, 256, 0, stream>>>(
        tmp, bucketBase, csr, offsets, counts, n);
    l1_edge_kernel<<<(n + 3) / 4, 256, 0, stream>>>(
        offsets, counts, csr, asrc1, adst1, h1, b1, W2, as2, ad2, h2, asrc2, adst2, n);
    l2_edge_kernel<<<(n + 3) / 4, 256, 0, stream>>>(
        offsets, counts, csr, asrc2, adst2, h2, b2, out, n);
}

// Round 12
// 175.542 us; speedup vs baseline: 1.3441x; 1.1909x over previous
//
#include <hip/hip_runtime.h>
#include <hip/hip_bf16.h>

#define IN_DIM 512
#define HEADS 8
#define HID 8
#define OUT_DIM 7
#define NEG_SLOPE 0.2f

typedef __attribute__((ext_vector_type(8))) short short8b;   // 8 bf16 (4 VGPR)
typedef __attribute__((ext_vector_type(4))) float f32x4;

// ---------------- W1 pack prep: fragment-major hi/lo bf16 ----------------
// bpack index ((chunk*4+T)*64 + lane)*8 + j  <->  W1[k*64+col],
// col = 16T + (lane&15), k = chunk*32 + 8*(lane>>4) + j.
// A B-fragment load is then 64 lanes x consecutive 16B = fully coalesced.
__global__ __launch_bounds__(256) void w1_pack_kernel(
    const float* __restrict__ W1, unsigned short* __restrict__ bhi,
    unsigned short* __restrict__ blo)
{
    int i = blockIdx.x * 256 + threadIdx.x;   // 0 .. 32767
    if (i >= IN_DIM * 64) return;
    int j = i & 7;
    int lane = (i >> 3) & 63;
    int T = (i >> 9) & 3;
    int chunk = i >> 11;
    int col = 16 * T + (lane & 15);
    int k = chunk * 32 + 8 * (lane >> 4) + j;
    float w = W1[k * 64 + col];
    unsigned u = __float_as_uint(w);
    unsigned hu = u & 0xFFFF0000u;
    float rem = w - __uint_as_float(hu);
    bhi[i] = (unsigned short)(hu >> 16);
    blo[i] = (unsigned short)(__float_as_uint(rem) >> 16);
}

// ---------------- GEMM1 via split-bf16 MFMA, K-split, coalesced loads ------
// Block = 16 rows; wave w owns k in [w*128,(w+1)*128).
// x staged coalesced -> wave-local LDS (no barrier); B from fragment-major pack.
// acc = xhi*whi + xhi*wlo + xlo*whi  (xlo*wlo dropped, ~2^-16 rel).
__global__ __launch_bounds__(256) void gemm1_kernel(
    const float* __restrict__ x,
    const unsigned short* __restrict__ bhi, const unsigned short* __restrict__ blo,
    const float* __restrict__ as1, const float* __restrict__ ad1,
    float* __restrict__ h1, float* __restrict__ asrc1, float* __restrict__ adst1,
    int n)
{
    __shared__ float lds[4][16][132];   // per-wave x stage; reused for partials
    int t = threadIdx.x;
    int wave = t >> 6, l = t & 63;
    int il = l & 15, g = l >> 4;
    int r0 = blockIdx.x * 16;
    int kw = wave * 128;

    // ---- coalesced stage: 8 float4 loads, lanes consecutive in k ----
    #pragma unroll
    for (int j = 0; j < 8; ++j) {
        int idx = j * 64 + l;          // 0..511
        int row = idx >> 5;            // 16 rows
        int kq = idx & 31;             // float4 slot in 128-float slice
        int gr = r0 + row; if (gr >= n) gr = n - 1;
        float4 v = *(const float4*)(x + (size_t)gr * IN_DIM + kw + kq * 4);
        *(float4*)(&lds[wave][row][kq * 4]) = v;
    }
    // wave-local: compiler inserts lgkmcnt waits; no __syncthreads needed.

    f32x4 acc[4] = {{0.f,0.f,0.f,0.f},{0.f,0.f,0.f,0.f},{0.f,0.f,0.f,0.f},{0.f,0.f,0.f,0.f}};

    #pragma unroll
    for (int it = 0; it < 4; ++it) {
        float av[8];
        *(float4*)(&av[0]) = *(const float4*)(&lds[wave][il][32 * it + 8 * g]);
        *(float4*)(&av[4]) = *(const float4*)(&lds[wave][il][32 * it + 8 * g + 4]);
        short8b Ahi, Alo;
        #pragma unroll
        for (int j = 0; j < 8; ++j) {
            unsigned u = __float_as_uint(av[j]);
            unsigned hu = u & 0xFFFF0000u;
            float rem = av[j] - __uint_as_float(hu);
            Ahi[j] = (short)(hu >> 16);
            Alo[j] = (short)(__float_as_uint(rem) >> 16);
        }
        int chunk = wave * 4 + it;
        const short8b* bh = (const short8b*)bhi + (size_t)(chunk * 4) * 64 + l;
        const short8b* bl = (const short8b*)blo + (size_t)(chunk * 4) * 64 + l;
        short8b Bh[4], Bl[4];
        #pragma unroll
        for (int T = 0; T < 4; ++T) { Bh[T] = bh[T * 64]; Bl[T] = bl[T * 64]; }
        #pragma unroll
        for (int T = 0; T < 4; ++T) {
            acc[T] = __builtin_amdgcn_mfma_f32_16x16x32_bf16(Alo, Bh[T], acc[T], 0, 0, 0);
            acc[T] = __builtin_amdgcn_mfma_f32_16x16x32_bf16(Ahi, Bl[T], acc[T], 0, 0, 0);
            acc[T] = __builtin_amdgcn_mfma_f32_16x16x32_bf16(Ahi, Bh[T], acc[T], 0, 0, 0);
        }
    }

    // D layout: col = 16T + il, row = 4g + r. Reuse lds region for partials.
    #pragma unroll
    for (int T = 0; T < 4; ++T)
        #pragma unroll
        for (int r = 0; r < 4; ++r)
            lds[wave][4 * g + r][16 * T + il] = acc[T][r];
    __syncthreads();

    // Reduce: thread t owns row t>>4, cols (t&15)*4 .. +3.
    int row = t >> 4, c0 = (t & 15) * 4;
    int grow = r0 + row;
    float v0 = lds[0][row][c0]     + lds[1][row][c0]     + lds[2][row][c0]     + lds[3][row][c0];
    float v1 = lds[0][row][c0 + 1] + lds[1][row][c0 + 1] + lds[2][row][c0 + 1] + lds[3][row][c0 + 1];
    float v2 = lds[0][row][c0 + 2] + lds[1][row][c0 + 2] + lds[2][row][c0 + 2] + lds[3][row][c0 + 2];
    float v3 = lds[0][row][c0 + 3] + lds[1][row][c0 + 3] + lds[2][row][c0 + 3] + lds[3][row][c0 + 3];
    if (grow < n) {
        *(float4*)(h1 + (size_t)grow * 64 + c0) = make_float4(v0, v1, v2, v3);
        float4 asv = *(const float4*)(as1 + c0);
        float4 adv = *(const float4*)(ad1 + c0);
        float pa = v0 * asv.x + v1 * asv.y + v2 * asv.z + v3 * asv.w;
        float pd = v0 * adv.x + v1 * adv.y + v2 * adv.z + v3 * adv.w;
        pa += __shfl_xor(pa, 1);
        pd += __shfl_xor(pd, 1);
        if ((t & 1) == 0) {
            int head = (t & 15) >> 1;
            asrc1[grow * 8 + head] = pa;
            adst1[grow * 8 + head] = pd;
        }
    }
}

// ---------------- CSR build: bucketed two-stage, 128-node buckets ----------
#define BSHIFT 7
#define BMASK 127
__global__ __launch_bounds__(256) void bucket_hist_kernel(
    const int* __restrict__ dst, int* __restrict__ bucketCounts, int E, int nbuck)
{
    __shared__ int cnt[512];
    int t = threadIdx.x;
    cnt[t] = 0; cnt[t + 256] = 0;
    __syncthreads();
    int i = blockIdx.x * blockDim.x + t;
    int stride = gridDim.x * blockDim.x;
    for (; i < E; i += stride) atomicAdd(&cnt[dst[i] >> BSHIFT], 1);
    __syncthreads();
    if (t < nbuck && cnt[t]) atomicAdd(&bucketCounts[t], cnt[t]);
    int t2 = t + 256;
    if (t2 < nbuck && cnt[t2]) atomicAdd(&bucketCounts[t2], cnt[t2]);
}

__global__ __launch_bounds__(512) void bucket_scan_kernel(
    const int* __restrict__ bucketCounts, int* __restrict__ bucketBase,
    int* __restrict__ bucketCursor, int nbuck)
{
    __shared__ int wsum[8];
    int t = threadIdx.x, lane = t & 63, w = t >> 6;
    int c = (t < nbuck) ? bucketCounts[t] : 0;
    int inc = c;
    #pragma unroll
    for (int d = 1; d < 64; d <<= 1) {
        int u = __shfl_up(inc, d);
        if (lane >= d) inc += u;
    }
    if (lane == 63) wsum[w] = inc;
    __syncthreads();
    if (t == 0) { int run = 0; for (int k = 0; k < 8; ++k) { int tmp = wsum[k]; wsum[k] = run; run += tmp; } }
    __syncthreads();
    int excl = inc - c + wsum[w];
    if (t < nbuck) { bucketBase[t] = excl; bucketCursor[t] = excl; }
    if (t == nbuck) bucketBase[t] = excl;
}

#define K3_EPT 16
__global__ __launch_bounds__(256) void coarse_scatter_kernel(
    const int* __restrict__ src, const int* __restrict__ dst,
    int* __restrict__ bucketCursor, unsigned int* __restrict__ tmp, int E)
{
    __shared__ int cnt[512];
    __shared__ int gbase[512];
    int t = threadIdx.x;
    cnt[t] = 0; cnt[t + 256] = 0;
    __syncthreads();
    int base = blockIdx.x * (256 * K3_EPT);
    unsigned int pk[K3_EPT];
    unsigned int meta[K3_EPT];
    #pragma unroll
    for (int j = 0; j < K3_EPT; ++j) {
        int i = base + t + j * 256;
        if (i < E) {
            int d = dst[i], s = src[i];
            int b = d >> BSHIFT;
            pk[j] = ((unsigned)s << 16) | (unsigned)(d & BMASK);
            int r = atomicAdd(&cnt[b], 1);
            meta[j] = ((unsigned)r << 9) | (unsigned)b;
        } else {
            meta[j] = 0xFFFFFFFFu; pk[j] = 0;
        }
    }
    __syncthreads();
    if (cnt[t] > 0) gbase[t] = atomicAdd(&bucketCursor[t], cnt[t]);
    int t2 = t + 256;
    if (cnt[t2] > 0) gbase[t2] = atomicAdd(&bucketCursor[t2], cnt[t2]);
    __syncthreads();
    #pragma unroll
    for (int j = 0; j < K3_EPT; ++j) {
        if (meta[j] != 0xFFFFFFFFu) {
            int b = meta[j] & 511;
            int r = meta[j] >> 9;
            tmp[gbase[b] + r] = pk[j];
        }
    }
}

__global__ __launch_bounds__(256) void fine_scatter_kernel(
    const unsigned int* __restrict__ tmp, const int* __restrict__ bucketBase,
    int* __restrict__ csr, int* __restrict__ offsets, int* __restrict__ counts, int n)
{
    __shared__ int cnt[128];
    __shared__ int cur[128];
    __shared__ int wsum[2];
    int b = blockIdx.x;
    int t = threadIdx.x, lane = t & 63, w = t >> 6;
    int beg = bucketBase[b], end = bucketBase[b + 1];
    if (t < 128) cnt[t] = 0;
    __syncthreads();
    for (int i = beg + t; i < end; i += 256)
        atomicAdd(&cnt[tmp[i] & BMASK], 1);
    __syncthreads();
    if (t < 128) {
        int c = cnt[t];
        int inc = c;
        #pragma unroll
        for (int d = 1; d < 64; d <<= 1) {
            int u = __shfl_up(inc, d);
            if (lane >= d) inc += u;
        }
        if (lane == 63) wsum[w] = inc;
        __syncthreads();
        if (t == 0) { int r0_ = wsum[0]; wsum[0] = 0; wsum[1] = r0_; }
        __syncthreads();
        int excl = inc - c + wsum[w];
        int node = b * 128 + t;
        if (node < n) { offsets[node] = beg + excl; counts[node] = c; }
        cur[t] = excl;
    } else {
        __syncthreads(); __syncthreads();
    }
    __syncthreads();
    for (int i = beg + t; i < end; i += 256) {
        unsigned int p = tmp[i];
        int r = atomicAdd(&cur[p & BMASK], 1);
        csr[beg + r] = (int)(p >> 16);
    }
}

// ---------------- Layer-1 edge kernel: single-pass (no max) ----------------
__global__ __launch_bounds__(256) void l1_edge_kernel(
    const int* __restrict__ offsets, const int* __restrict__ counts,
    const int* __restrict__ csr,
    const float* __restrict__ asrc1, const float* __restrict__ adst1,
    const float* __restrict__ h1, const float* __restrict__ b1,
    const float* __restrict__ W2, const float* __restrict__ as2,
    const float* __restrict__ ad2,
    float* __restrict__ h2, float* __restrict__ asrc2, float* __restrict__ adst2,
    int n)
{
    __shared__ float w2t[8][64];
    __shared__ float s_as2[8], s_ad2[8], s_b1[64];
    int t = threadIdx.x;
    if (t < 64) {
        #pragma unroll
        for (int j = 0; j < OUT_DIM; ++j) w2t[j][t] = W2[t * OUT_DIM + j];
        s_b1[t] = b1[t];
        if (t < OUT_DIM) { s_as2[t] = as2[t]; s_ad2[t] = ad2[t]; }
    }
    __syncthreads();

    int lane = t & 63;
    int node = blockIdx.x * 4 + (t >> 6);
    if (node >= n) return;
    int beg = offsets[node];
    int deg = counts[node];
    int q = lane >> 4;
    int il = lane & 15;
    int c0 = il * 4;
    int head = il >> 1;
    float adv = adst1[node * 8 + head];

    float4 acc = make_float4(0.f, 0.f, 0.f, 0.f);
    float ssum = 0.f;
    if (q == 0) {
        float e = asrc1[node * 8 + head] + adv;
        e = e > 0.f ? e : NEG_SLOPE * e;
        float p = __expf(e);
        float4 hv = *(const float4*)(h1 + (size_t)node * 64 + c0);
        acc.x = p * hv.x; acc.y = p * hv.y; acc.z = p * hv.z; acc.w = p * hv.w;
        ssum = p;
    }
    int j = q;
    for (; j + 4 < deg; j += 8) {
        int s0 = csr[beg + j], s1 = csr[beg + j + 4];
        float a0 = asrc1[s0 * 8 + head], a1 = asrc1[s1 * 8 + head];
        float4 g0 = *(const float4*)(h1 + (size_t)s0 * 64 + c0);
        float4 g1 = *(const float4*)(h1 + (size_t)s1 * 64 + c0);
        float e0 = a0 + adv; e0 = e0 > 0.f ? e0 : NEG_SLOPE * e0;
        float e1 = a1 + adv; e1 = e1 > 0.f ? e1 : NEG_SLOPE * e1;
        float p0 = __expf(e0), p1 = __expf(e1);
        acc.x = fmaf(p0, g0.x, acc.x); acc.y = fmaf(p0, g0.y, acc.y);
        acc.z = fmaf(p0, g0.z, acc.z); acc.w = fmaf(p0, g0.w, acc.w);
        acc.x = fmaf(p1, g1.x, acc.x); acc.y = fmaf(p1, g1.y, acc.y);
        acc.z = fmaf(p1, g1.z, acc.z); acc.w = fmaf(p1, g1.w, acc.w);
        ssum += p0 + p1;
    }
    for (; j < deg; j += 4) {
        int sn = csr[beg + j];
        float a = asrc1[sn * 8 + head];
        float4 g = *(const float4*)(h1 + (size_t)sn * 64 + c0);
        float e = a + adv; e = e > 0.f ? e : NEG_SLOPE * e;
        float p = __expf(e);
        acc.x = fmaf(p, g.x, acc.x); acc.y = fmaf(p, g.y, acc.y);
        acc.z = fmaf(p, g.z, acc.z); acc.w = fmaf(p, g.w, acc.w);
        ssum += p;
    }
    acc.x += __shfl_xor(acc.x, 16); acc.x += __shfl_xor(acc.x, 32);
    acc.y += __shfl_xor(acc.y, 16); acc.y += __shfl_xor(acc.y, 32);
    acc.z += __shfl_xor(acc.z, 16); acc.z += __shfl_xor(acc.z, 32);
    acc.w += __shfl_xor(acc.w, 16); acc.w += __shfl_xor(acc.w, 32);
    ssum  += __shfl_xor(ssum, 16);  ssum  += __shfl_xor(ssum, 32);
    float inv = 1.f / fmaxf(ssum, 1e-16f);

    float4 bv = *(const float4*)(&s_b1[c0]);
    float v0 = acc.x * inv + bv.x;
    float v1 = acc.y * inv + bv.y;
    float v2 = acc.z * inv + bv.z;
    float v3 = acc.w * inv + bv.w;
    v0 = v0 > 0.f ? v0 : __expf(v0) - 1.f;
    v1 = v1 > 0.f ? v1 : __expf(v1) - 1.f;
    v2 = v2 > 0.f ? v2 : __expf(v2) - 1.f;
    v3 = v3 > 0.f ? v3 : __expf(v3) - 1.f;

    float hj[OUT_DIM];
    #pragma unroll
    for (int jj = 0; jj < OUT_DIM; ++jj) {
        float4 wv = *(const float4*)(&w2t[jj][c0]);
        float p = v0 * wv.x + v1 * wv.y + v2 * wv.z + v3 * wv.w;
        p += __shfl_xor(p, 1);
        p += __shfl_xor(p, 2);
        p += __shfl_xor(p, 4);
        p += __shfl_xor(p, 8);
        hj[jj] = p;
    }
    float a_s = 0.f, a_d = 0.f;
    #pragma unroll
    for (int jj = 0; jj < OUT_DIM; ++jj) { a_s += hj[jj] * s_as2[jj]; a_d += hj[jj] * s_ad2[jj]; }
    if (lane < 8) h2[node * 8 + lane] = (lane < OUT_DIM) ? hj[lane] : 0.f;
    if (lane == 0) { asrc2[node] = a_s; adst2[node] = a_d; }
}

// ---------------- Layer-2 edge kernel: single-pass -> final logits --------
__global__ __launch_bounds__(256) void l2_edge_kernel(
    const int* __restrict__ offsets, const int* __restrict__ counts,
    const int* __restrict__ csr,
    const float* __restrict__ asrc2, const float* __restrict__ adst2,
    const float* __restrict__ h2, const float* __restrict__ b2,
    float* __restrict__ out, int n)
{
    int t = threadIdx.x, lane = t & 63;
    int node = blockIdx.x * 4 + (t >> 6);
    if (node >= n) return;
    int beg = offsets[node];
    int deg = counts[node];
    float adv = adst2[node];

    int c = lane & 7, slot = lane >> 3;
    float acc = 0.f, ssum = 0.f;
    if (slot == 0) {
        float e = asrc2[node] + adv;
        e = e > 0.f ? e : NEG_SLOPE * e;
        float p = __expf(e);
        acc = p * h2[node * 8 + c];
        ssum = p;
    }
    int j = slot;
    for (; j + 8 < deg; j += 16) {
        int s0 = csr[beg + j], s1 = csr[beg + j + 8];
        float a0 = asrc2[s0], a1 = asrc2[s1];
        float g0 = h2[s0 * 8 + c], g1 = h2[s1 * 8 + c];
        float e0 = a0 + adv; e0 = e0 > 0.f ? e0 : NEG_SLOPE * e0;
        float e1 = a1 + adv; e1 = e1 > 0.f ? e1 : NEG_SLOPE * e1;
        float p0 = __expf(e0), p1 = __expf(e1);
        acc = fmaf(p0, g0, acc); acc = fmaf(p1, g1, acc);
        ssum += p0 + p1;
    }
    for (; j < deg; j += 8) {
        int sn = csr[beg + j];
        float e = asrc2[sn] + adv;
        e = e > 0.f ? e : NEG_SLOPE * e;
        float p = __expf(e);
        acc = fmaf(p, h2[sn * 8 + c], acc);
        ssum += p;
    }
    acc  += __shfl_xor(acc, 8);  acc  += __shfl_xor(acc, 16);  acc  += __shfl_xor(acc, 32);
    ssum += __shfl_xor(ssum, 8); ssum += __shfl_xor(ssum, 16); ssum += __shfl_xor(ssum, 32);
    float inv = 1.f / fmaxf(ssum, 1e-16f);
    if (lane < OUT_DIM) out[(size_t)node * OUT_DIM + lane] = acc * inv + b2[lane];
}

// ---------------- launch ----------------
static inline size_t rup256(size_t x) { return (x + 255) & ~(size_t)255; }

extern "C" void kernel_launch(void* const* d_in, const int* in_sizes, int n_in,
                              void* d_out, int out_size, void* d_ws, size_t ws_size,
                              hipStream_t stream)
{
    int n = in_sizes[0] / IN_DIM;       // 50000
    int E = in_sizes[1] / 2;            // 1600000
    int nbuck = (n + BMASK) >> BSHIFT;  // 391

    const float* x   = (const float*)d_in[0];
    const int*   ei  = (const int*)d_in[1];
    const int*   srcv = ei;
    const int*   dstv = ei + E;
    const float* W1  = (const float*)d_in[2];
    const float* as1 = (const float*)d_in[3];
    const float* ad1 = (const float*)d_in[4];
    const float* b1  = (const float*)d_in[5];
    const float* W2  = (const float*)d_in[6];
    const float* as2 = (const float*)d_in[7];
    const float* ad2 = (const float*)d_in[8];
    const float* b2  = (const float*)d_in[9];
    float* out = (float*)d_out;

    char* p = (char*)d_ws;
    auto alloc = [&](size_t bytes) { char* q = p; p += rup256(bytes); return (void*)q; };
    float* h1      = (float*)alloc((size_t)n * 64 * 4);
    float* asrc1   = (float*)alloc((size_t)n * 8 * 4);
    float* adst1   = (float*)alloc((size_t)n * 8 * 4);
    float* h2      = (float*)alloc((size_t)n * 8 * 4);
    float* asrc2   = (float*)alloc((size_t)n * 4);
    float* adst2   = (float*)alloc((size_t)n * 4);
    int*   counts  = (int*)alloc((size_t)n * 4);
    int*   offsets = (int*)alloc(((size_t)n + 1) * 4);
    int*   csr     = (int*)alloc((size_t)E * 4);
    unsigned int* tmp = (unsigned int*)alloc((size_t)E * 4);
    int*   bucketCounts = (int*)alloc(512 * 4);
    int*   bucketBase   = (int*)alloc(513 * 4);
    int*   bucketCursor = (int*)alloc(512 * 4);
    unsigned short* bhi = (unsigned short*)alloc((size_t)IN_DIM * 64 * 2);
    unsigned short* blo = (unsigned short*)alloc((size_t)IN_DIM * 64 * 2);

    hipMemsetAsync(bucketCounts, 0, 512 * 4, stream);
    bucket_hist_kernel<<<512, 256, 0, stream>>>(dstv, bucketCounts, E, nbuck);
    w1_pack_kernel<<<(IN_DIM * 64 + 255) / 256, 256, 0, stream>>>(W1, bhi, blo);
    gemm1_kernel<<<(n + 15) / 16, 256, 0, stream>>>(
        x, bhi, blo, as1, ad1, h1, asrc1, adst1, n);
    bucket_scan_kernel<<<1, 512, 0, stream>>>(bucketCounts, bucketBase, bucketCursor, nbuck);
    coarse_scatter_kernel<<<(E + 256 * K3_EPT - 1) / (256 * K3_EPT), 256, 0, stream>>>(
        srcv, dstv, bucketCursor, tmp, E);
    fine_scatter_kernel<<<nbuck, 256, 0, stream>>>(
        tmp, bucketBase, csr, offsets, counts, n);
    l1_edge_kernel<<<(n + 3) / 4, 256, 0, stream>>>(
        offsets, counts, csr, asrc1, adst1, h1, b1, W2, as2, ad2, h2, asrc2, adst2, n);
    l2_edge_kernel<<<(n + 3) / 4, 256, 0, stream>>>(
        offsets, counts, csr, asrc2, adst2, h2, b2, out, n);
}

// Round 14
// 173.492 us; speedup vs baseline: 1.3600x; 1.0118x over previous
//
#include <hip/hip_runtime.h>
#include <hip/hip_bf16.h>

#define IN_DIM 512
#define HEADS 8
#define HID 8
#define OUT_DIM 7
#define NEG_SLOPE 0.2f

typedef __attribute__((ext_vector_type(8))) short short8b;   // 8 bf16 (4 VGPR)
typedef __attribute__((ext_vector_type(4))) float f32x4;

// ---------------- W1 pack prep: fragment-major hi/lo bf16 ----------------
__global__ __launch_bounds__(256) void w1_pack_kernel(
    const float* __restrict__ W1, unsigned short* __restrict__ bhi,
    unsigned short* __restrict__ blo)
{
    int i = blockIdx.x * 256 + threadIdx.x;   // 0 .. 32767
    if (i >= IN_DIM * 64) return;
    int j = i & 7;
    int lane = (i >> 3) & 63;
    int T = (i >> 9) & 3;
    int chunk = i >> 11;
    int col = 16 * T + (lane & 15);
    int k = chunk * 32 + 8 * (lane >> 4) + j;
    float w = W1[k * 64 + col];
    unsigned u = __float_as_uint(w);
    unsigned hu = u & 0xFFFF0000u;
    float rem = w - __uint_as_float(hu);
    bhi[i] = (unsigned short)(hu >> 16);
    blo[i] = (unsigned short)(__float_as_uint(rem) >> 16);
}

// ---------------- GEMM1 via split-bf16 MFMA, K-split, coalesced loads ------
__global__ __launch_bounds__(256) void gemm1_kernel(
    const float* __restrict__ x,
    const unsigned short* __restrict__ bhi, const unsigned short* __restrict__ blo,
    const float* __restrict__ as1, const float* __restrict__ ad1,
    float* __restrict__ h1, float* __restrict__ asrc1, float* __restrict__ adst1,
    int n)
{
    __shared__ float lds[4][16][132];   // per-wave x stage; reused for partials
    int t = threadIdx.x;
    int wave = t >> 6, l = t & 63;
    int il = l & 15, g = l >> 4;
    int r0 = blockIdx.x * 16;
    int kw = wave * 128;

    #pragma unroll
    for (int j = 0; j < 8; ++j) {
        int idx = j * 64 + l;          // 0..511
        int row = idx >> 5;
        int kq = idx & 31;
        int gr = r0 + row; if (gr >= n) gr = n - 1;
        float4 v = *(const float4*)(x + (size_t)gr * IN_DIM + kw + kq * 4);
        *(float4*)(&lds[wave][row][kq * 4]) = v;
    }

    f32x4 acc[4] = {{0.f,0.f,0.f,0.f},{0.f,0.f,0.f,0.f},{0.f,0.f,0.f,0.f},{0.f,0.f,0.f,0.f}};

    #pragma unroll
    for (int it = 0; it < 4; ++it) {
        float av[8];
        *(float4*)(&av[0]) = *(const float4*)(&lds[wave][il][32 * it + 8 * g]);
        *(float4*)(&av[4]) = *(const float4*)(&lds[wave][il][32 * it + 8 * g + 4]);
        short8b Ahi, Alo;
        #pragma unroll
        for (int j = 0; j < 8; ++j) {
            unsigned u = __float_as_uint(av[j]);
            unsigned hu = u & 0xFFFF0000u;
            float rem = av[j] - __uint_as_float(hu);
            Ahi[j] = (short)(hu >> 16);
            Alo[j] = (short)(__float_as_uint(rem) >> 16);
        }
        int chunk = wave * 4 + it;
        const short8b* bh = (const short8b*)bhi + (size_t)(chunk * 4) * 64 + l;
        const short8b* bl = (const short8b*)blo + (size_t)(chunk * 4) * 64 + l;
        short8b Bh[4], Bl[4];
        #pragma unroll
        for (int T = 0; T < 4; ++T) { Bh[T] = bh[T * 64]; Bl[T] = bl[T * 64]; }
        #pragma unroll
        for (int T = 0; T < 4; ++T) {
            acc[T] = __builtin_amdgcn_mfma_f32_16x16x32_bf16(Alo, Bh[T], acc[T], 0, 0, 0);
            acc[T] = __builtin_amdgcn_mfma_f32_16x16x32_bf16(Ahi, Bl[T], acc[T], 0, 0, 0);
            acc[T] = __builtin_amdgcn_mfma_f32_16x16x32_bf16(Ahi, Bh[T], acc[T], 0, 0, 0);
        }
    }

    #pragma unroll
    for (int T = 0; T < 4; ++T)
        #pragma unroll
        for (int r = 0; r < 4; ++r)
            lds[wave][4 * g + r][16 * T + il] = acc[T][r];
    __syncthreads();

    int row = t >> 4, c0 = (t & 15) * 4;
    int grow = r0 + row;
    float v0 = lds[0][row][c0]     + lds[1][row][c0]     + lds[2][row][c0]     + lds[3][row][c0];
    float v1 = lds[0][row][c0 + 1] + lds[1][row][c0 + 1] + lds[2][row][c0 + 1] + lds[3][row][c0 + 1];
    float v2 = lds[0][row][c0 + 2] + lds[1][row][c0 + 2] + lds[2][row][c0 + 2] + lds[3][row][c0 + 2];
    float v3 = lds[0][row][c0 + 3] + lds[1][row][c0 + 3] + lds[2][row][c0 + 3] + lds[3][row][c0 + 3];
    if (grow < n) {
        *(float4*)(h1 + (size_t)grow * 64 + c0) = make_float4(v0, v1, v2, v3);
        float4 asv = *(const float4*)(as1 + c0);
        float4 adv = *(const float4*)(ad1 + c0);
        float pa = v0 * asv.x + v1 * asv.y + v2 * asv.z + v3 * asv.w;
        float pd = v0 * adv.x + v1 * adv.y + v2 * adv.z + v3 * adv.w;
        pa += __shfl_xor(pa, 1);
        pd += __shfl_xor(pd, 1);
        if ((t & 1) == 0) {
            int head = (t & 15) >> 1;
            asrc1[grow * 8 + head] = pa;
            adst1[grow * 8 + head] = pd;
        }
    }
}

// ---------------- CSR build: bucketed two-stage, 128-node buckets ----------
#define BSHIFT 7
#define BMASK 127
__global__ __launch_bounds__(256) void bucket_hist_kernel(
    const int* __restrict__ dst, int* __restrict__ bucketCounts, int E, int nbuck)
{
    __shared__ int cnt[512];
    int t = threadIdx.x;
    cnt[t] = 0; cnt[t + 256] = 0;
    __syncthreads();
    int i = blockIdx.x * blockDim.x + t;
    int stride = gridDim.x * blockDim.x;
    for (; i < E; i += stride) atomicAdd(&cnt[dst[i] >> BSHIFT], 1);
    __syncthreads();
    if (t < nbuck && cnt[t]) atomicAdd(&bucketCounts[t], cnt[t]);
    int t2 = t + 256;
    if (t2 < nbuck && cnt[t2]) atomicAdd(&bucketCounts[t2], cnt[t2]);
}

__global__ __launch_bounds__(512) void bucket_scan_kernel(
    const int* __restrict__ bucketCounts, int* __restrict__ bucketBase,
    int* __restrict__ bucketCursor, int nbuck)
{
    __shared__ int wsum[8];
    int t = threadIdx.x, lane = t & 63, w = t >> 6;
    int c = (t < nbuck) ? bucketCounts[t] : 0;
    int inc = c;
    #pragma unroll
    for (int d = 1; d < 64; d <<= 1) {
        int u = __shfl_up(inc, d);
        if (lane >= d) inc += u;
    }
    if (lane == 63) wsum[w] = inc;
    __syncthreads();
    if (t == 0) { int run = 0; for (int k = 0; k < 8; ++k) { int tmp = wsum[k]; wsum[k] = run; run += tmp; } }
    __syncthreads();
    int excl = inc - c + wsum[w];
    if (t < nbuck) { bucketBase[t] = excl; bucketCursor[t] = excl; }
    if (t == nbuck) bucketBase[t] = excl;
}

#define K3_EPT 16
__global__ __launch_bounds__(256) void coarse_scatter_kernel(
    const int* __restrict__ src, const int* __restrict__ dst,
    int* __restrict__ bucketCursor, unsigned int* __restrict__ tmp, int E)
{
    __shared__ int cnt[512];
    __shared__ int gbase[512];
    int t = threadIdx.x;
    cnt[t] = 0; cnt[t + 256] = 0;
    __syncthreads();
    int base = blockIdx.x * (256 * K3_EPT);
    unsigned int pk[K3_EPT];
    unsigned int meta[K3_EPT];
    #pragma unroll
    for (int j = 0; j < K3_EPT; ++j) {
        int i = base + t + j * 256;
        if (i < E) {
            int d = dst[i], s = src[i];
            int b = d >> BSHIFT;
            pk[j] = ((unsigned)s << 16) | (unsigned)(d & BMASK);
            int r = atomicAdd(&cnt[b], 1);
            meta[j] = ((unsigned)r << 9) | (unsigned)b;
        } else {
            meta[j] = 0xFFFFFFFFu; pk[j] = 0;
        }
    }
    __syncthreads();
    if (cnt[t] > 0) gbase[t] = atomicAdd(&bucketCursor[t], cnt[t]);
    int t2 = t + 256;
    if (cnt[t2] > 0) gbase[t2] = atomicAdd(&bucketCursor[t2], cnt[t2]);
    __syncthreads();
    #pragma unroll
    for (int j = 0; j < K3_EPT; ++j) {
        if (meta[j] != 0xFFFFFFFFu) {
            int b = meta[j] & 511;
            int r = meta[j] >> 9;
            tmp[gbase[b] + r] = pk[j];
        }
    }
}

__global__ __launch_bounds__(256) void fine_scatter_kernel(
    const unsigned int* __restrict__ tmp, const int* __restrict__ bucketBase,
    int* __restrict__ csr, int* __restrict__ offsets, int* __restrict__ counts, int n)
{
    __shared__ int cnt[128];
    __shared__ int cur[128];
    __shared__ int wsum[2];
    int b = blockIdx.x;
    int t = threadIdx.x, lane = t & 63, w = t >> 6;
    int beg = bucketBase[b], end = bucketBase[b + 1];
    if (t < 128) cnt[t] = 0;
    __syncthreads();
    for (int i = beg + t; i < end; i += 256)
        atomicAdd(&cnt[tmp[i] & BMASK], 1);
    __syncthreads();
    if (t < 128) {
        int c = cnt[t];
        int inc = c;
        #pragma unroll
        for (int d = 1; d < 64; d <<= 1) {
            int u = __shfl_up(inc, d);
            if (lane >= d) inc += u;
        }
        if (lane == 63) wsum[w] = inc;
        __syncthreads();
        if (t == 0) { int r0_ = wsum[0]; wsum[0] = 0; wsum[1] = r0_; }
        __syncthreads();
        int excl = inc - c + wsum[w];
        int node = b * 128 + t;
        if (node < n) { offsets[node] = beg + excl; counts[node] = c; }
        cur[t] = excl;
    } else {
        __syncthreads(); __syncthreads();
    }
    __syncthreads();
    for (int i = beg + t; i < end; i += 256) {
        unsigned int p = tmp[i];
        int r = atomicAdd(&cur[p & BMASK], 1);
        csr[beg + r] = (int)(p >> 16);
    }
}

// ---------------- Layer-1 edge kernel: single-pass, LDS csr stage + deep MLP
// lane = q*16 + il; q = edge slot (4), il*4 = channel quad.
// csr[beg..beg+63] staged once (coalesced) into wave-local LDS; reads are
// exec-mask independent (unlike shfl: bpermute from an exited lane returns 0).
__global__ __launch_bounds__(256) void l1_edge_kernel(
    const int* __restrict__ offsets, const int* __restrict__ counts,
    const int* __restrict__ csr,
    const float* __restrict__ asrc1, const float* __restrict__ adst1,
    const float* __restrict__ h1, const float* __restrict__ b1,
    const float* __restrict__ W2, const float* __restrict__ as2,
    const float* __restrict__ ad2,
    float* __restrict__ h2, float* __restrict__ asrc2, float* __restrict__ adst2,
    int n)
{
    __shared__ float w2t[8][64];
    __shared__ float s_as2[8], s_ad2[8], s_b1[64];
    __shared__ int csr_s[4][64];
    int t = threadIdx.x;
    if (t < 64) {
        #pragma unroll
        for (int j = 0; j < OUT_DIM; ++j) w2t[j][t] = W2[t * OUT_DIM + j];
        s_b1[t] = b1[t];
        if (t < OUT_DIM) { s_as2[t] = as2[t]; s_ad2[t] = ad2[t]; }
    }
    __syncthreads();

    int lane = t & 63;
    int nl = t >> 6;
    int node = blockIdx.x * 4 + nl;
    if (node >= n) return;
    int beg = offsets[node];
    int deg = counts[node];
    int q = lane >> 4;
    int il = lane & 15;
    int c0 = il * 4;
    int head = il >> 1;
    float adv = adst1[node * 8 + head];

    // stage up to 64 edge sources into wave-local LDS (coalesced, once)
    if (lane < deg) csr_s[nl][lane] = csr[beg + lane];
    int deg_r = deg < 64 ? deg : 64;
    const int* cs = &csr_s[nl][0];

    float4 acc = make_float4(0.f, 0.f, 0.f, 0.f);
    float ssum = 0.f;
    if (q == 0) {   // self loop
        float e = asrc1[node * 8 + head] + adv;
        e = e > 0.f ? e : NEG_SLOPE * e;
        float p = __expf(e);
        float4 hv = *(const float4*)(h1 + (size_t)node * 64 + c0);
        acc.x = p * hv.x; acc.y = p * hv.y; acc.z = p * hv.z; acc.w = p * hv.w;
        ssum = p;
    }
    int j = q;
    // 4 edges per quarter per round: 16 edges, ~20 lines in flight
    for (; j + 12 < deg_r; j += 16) {
        int s0 = cs[j];
        int s1 = cs[j + 4];
        int s2 = cs[j + 8];
        int s3 = cs[j + 12];
        float a0 = asrc1[s0 * 8 + head], a1 = asrc1[s1 * 8 + head];
        float a2 = asrc1[s2 * 8 + head], a3 = asrc1[s3 * 8 + head];
        float4 g0 = *(const float4*)(h1 + (size_t)s0 * 64 + c0);
        float4 g1 = *(const float4*)(h1 + (size_t)s1 * 64 + c0);
        float4 g2 = *(const float4*)(h1 + (size_t)s2 * 64 + c0);
        float4 g3 = *(const float4*)(h1 + (size_t)s3 * 64 + c0);
        float e0 = a0 + adv; e0 = e0 > 0.f ? e0 : NEG_SLOPE * e0;
        float e1 = a1 + adv; e1 = e1 > 0.f ? e1 : NEG_SLOPE * e1;
        float e2 = a2 + adv; e2 = e2 > 0.f ? e2 : NEG_SLOPE * e2;
        float e3 = a3 + adv; e3 = e3 > 0.f ? e3 : NEG_SLOPE * e3;
        float p0 = __expf(e0), p1 = __expf(e1);
        float p2 = __expf(e2), p3 = __expf(e3);
        acc.x = fmaf(p0, g0.x, acc.x); acc.y = fmaf(p0, g0.y, acc.y);
        acc.z = fmaf(p0, g0.z, acc.z); acc.w = fmaf(p0, g0.w, acc.w);
        acc.x = fmaf(p1, g1.x, acc.x); acc.y = fmaf(p1, g1.y, acc.y);
        acc.z = fmaf(p1, g1.z, acc.z); acc.w = fmaf(p1, g1.w, acc.w);
        acc.x = fmaf(p2, g2.x, acc.x); acc.y = fmaf(p2, g2.y, acc.y);
        acc.z = fmaf(p2, g2.z, acc.z); acc.w = fmaf(p2, g2.w, acc.w);
        acc.x = fmaf(p3, g3.x, acc.x); acc.y = fmaf(p3, g3.y, acc.y);
        acc.z = fmaf(p3, g3.z, acc.z); acc.w = fmaf(p3, g3.w, acc.w);
        ssum += (p0 + p1) + (p2 + p3);
    }
    for (; j < deg_r; j += 4) {      // staged tail
        int sn = cs[j];
        float a = asrc1[sn * 8 + head];
        float4 g = *(const float4*)(h1 + (size_t)sn * 64 + c0);
        float e = a + adv; e = e > 0.f ? e : NEG_SLOPE * e;
        float p = __expf(e);
        acc.x = fmaf(p, g.x, acc.x); acc.y = fmaf(p, g.y, acc.y);
        acc.z = fmaf(p, g.z, acc.z); acc.w = fmaf(p, g.w, acc.w);
        ssum += p;
    }
    for (; j < deg; j += 4) {        // rare deg>64 overflow: direct loads
        int sn = csr[beg + j];
        float a = asrc1[sn * 8 + head];
        float4 g = *(const float4*)(h1 + (size_t)sn * 64 + c0);
        float e = a + adv; e = e > 0.f ? e : NEG_SLOPE * e;
        float p = __expf(e);
        acc.x = fmaf(p, g.x, acc.x); acc.y = fmaf(p, g.y, acc.y);
        acc.z = fmaf(p, g.z, acc.z); acc.w = fmaf(p, g.w, acc.w);
        ssum += p;
    }
    // combine quarters
    acc.x += __shfl_xor(acc.x, 16); acc.x += __shfl_xor(acc.x, 32);
    acc.y += __shfl_xor(acc.y, 16); acc.y += __shfl_xor(acc.y, 32);
    acc.z += __shfl_xor(acc.z, 16); acc.z += __shfl_xor(acc.z, 32);
    acc.w += __shfl_xor(acc.w, 16); acc.w += __shfl_xor(acc.w, 32);
    ssum  += __shfl_xor(ssum, 16);  ssum  += __shfl_xor(ssum, 32);
    float inv = 1.f / fmaxf(ssum, 1e-16f);

    float4 bv = *(const float4*)(&s_b1[c0]);
    float v0 = acc.x * inv + bv.x;
    float v1 = acc.y * inv + bv.y;
    float v2 = acc.z * inv + bv.z;
    float v3 = acc.w * inv + bv.w;
    v0 = v0 > 0.f ? v0 : __expf(v0) - 1.f;
    v1 = v1 > 0.f ? v1 : __expf(v1) - 1.f;
    v2 = v2 > 0.f ? v2 : __expf(v2) - 1.f;
    v3 = v3 > 0.f ? v3 : __expf(v3) - 1.f;

    float hj[OUT_DIM];
    #pragma unroll
    for (int jj = 0; jj < OUT_DIM; ++jj) {
        float4 wv = *(const float4*)(&w2t[jj][c0]);
        float p = v0 * wv.x + v1 * wv.y + v2 * wv.z + v3 * wv.w;
        p += __shfl_xor(p, 1);
        p += __shfl_xor(p, 2);
        p += __shfl_xor(p, 4);
        p += __shfl_xor(p, 8);
        hj[jj] = p;
    }
    float a_s = 0.f, a_d = 0.f;
    #pragma unroll
    for (int jj = 0; jj < OUT_DIM; ++jj) { a_s += hj[jj] * s_as2[jj]; a_d += hj[jj] * s_ad2[jj]; }
    if (lane < 8) h2[node * 8 + lane] = (lane < OUT_DIM) ? hj[lane] : 0.f;
    if (lane == 0) { asrc2[node] = a_s; adst2[node] = a_d; }
}

// ---------------- Layer-2 edge kernel: single-pass -> final logits --------
__global__ __launch_bounds__(256) void l2_edge_kernel(
    const int* __restrict__ offsets, const int* __restrict__ counts,
    const int* __restrict__ csr,
    const float* __restrict__ asrc2, const float* __restrict__ adst2,
    const float* __restrict__ h2, const float* __restrict__ b2,
    float* __restrict__ out, int n)
{
    int t = threadIdx.x, lane = t & 63;
    int node = blockIdx.x * 4 + (t >> 6);
    if (node >= n) return;
    int beg = offsets[node];
    int deg = counts[node];
    float adv = adst2[node];

    int c = lane & 7, slot = lane >> 3;
    float acc = 0.f, ssum = 0.f;
    if (slot == 0) {
        float e = asrc2[node] + adv;
        e = e > 0.f ? e : NEG_SLOPE * e;
        float p = __expf(e);
        acc = p * h2[node * 8 + c];
        ssum = p;
    }
    int j = slot;
    for (; j + 8 < deg; j += 16) {
        int s0 = csr[beg + j], s1 = csr[beg + j + 8];
        float a0 = asrc2[s0], a1 = asrc2[s1];
        float g0 = h2[s0 * 8 + c], g1 = h2[s1 * 8 + c];
        float e0 = a0 + adv; e0 = e0 > 0.f ? e0 : NEG_SLOPE * e0;
        float e1 = a1 + adv; e1 = e1 > 0.f ? e1 : NEG_SLOPE * e1;
        float p0 = __expf(e0), p1 = __expf(e1);
        acc = fmaf(p0, g0, acc); acc = fmaf(p1, g1, acc);
        ssum += p0 + p1;
    }
    for (; j < deg; j += 8) {
        int sn = csr[beg + j];
        float e = asrc2[sn] + adv;
        e = e > 0.f ? e : NEG_SLOPE * e;
        float p = __expf(e);
        acc = fmaf(p, h2[sn * 8 + c], acc);
        ssum += p;
    }
    acc  += __shfl_xor(acc, 8);  acc  += __shfl_xor(acc, 16);  acc  += __shfl_xor(acc, 32);
    ssum += __shfl_xor(ssum, 8); ssum += __shfl_xor(ssum, 16); ssum += __shfl_xor(ssum, 32);
    float inv = 1.f / fmaxf(ssum, 1e-16f);
    if (lane < OUT_DIM) out[(size_t)node * OUT_DIM + lane] = acc * inv + b2[lane];
}

// ---------------- launch ----------------
static inline size_t rup256(size_t x) { return (x + 255) & ~(size_t)255; }

extern "C" void kernel_launch(void* const* d_in, const int* in_sizes, int n_in,
                              void* d_out, int out_size, void* d_ws, size_t ws_size,
                              hipStream_t stream)
{
    int n = in_sizes[0] / IN_DIM;       // 50000
    int E = in_sizes[1] / 2;            // 1600000
    int nbuck = (n + BMASK) >> BSHIFT;  // 391

    const float* x   = (const float*)d_in[0];
    const int*   ei  = (const int*)d_in[1];
    const int*   srcv = ei;
    const int*   dstv = ei + E;
    const float* W1  = (const float*)d_in[2];
    const float* as1 = (const float*)d_in[3];
    const float* ad1 = (const float*)d_in[4];
    const float* b1  = (const float*)d_in[5];
    const float* W2  = (const float*)d_in[6];
    const float* as2 = (const float*)d_in[7];
    const float* ad2 = (const float*)d_in[8];
    const float* b2  = (const float*)d_in[9];
    float* out = (float*)d_out;

    char* p = (char*)d_ws;
    auto alloc = [&](size_t bytes) { char* q = p; p += rup256(bytes); return (void*)q; };
    float* h1      = (float*)alloc((size_t)n * 64 * 4);
    float* asrc1   = (float*)alloc((size_t)n * 8 * 4);
    float* adst1   = (float*)alloc((size_t)n * 8 * 4);
    float* h2      = (float*)alloc((size_t)n * 8 * 4);
    float* asrc2   = (float*)alloc((size_t)n * 4);
    float* adst2   = (float*)alloc((size_t)n * 4);
    int*   counts  = (int*)alloc((size_t)n * 4);
    int*   offsets = (int*)alloc(((size_t)n + 1) * 4);
    int*   csr     = (int*)alloc((size_t)E * 4);
    unsigned int* tmp = (unsigned int*)alloc((size_t)E * 4);
    int*   bucketCounts = (int*)alloc(512 * 4);
    int*   bucketBase   = (int*)alloc(513 * 4);
    int*   bucketCursor = (int*)alloc(512 * 4);
    unsigned short* bhi = (unsigned short*)alloc((size_t)IN_DIM * 64 * 2);
    unsigned short* blo = (unsigned short*)alloc((size_t)IN_DIM * 64 * 2);

    hipMemsetAsync(bucketCounts, 0, 512 * 4, stream);
    bucket_hist_kernel<<<512, 256, 0, stream>>>(dstv, bucketCounts, E, nbuck);
    w1_pack_kernel<<<(IN_DIM * 64 + 255) / 256, 256, 0, stream>>>(W1, bhi, blo);
    gemm1_kernel<<<(n + 15) / 16, 256, 0, stream>>>(
        x, bhi, blo, as1, ad1, h1, asrc1, adst1, n);
    bucket_scan_kernel<<<1, 512, 0, stream>>>(bucketCounts, bucketBase, bucketCursor, nbuck);
    coarse_scatter_kernel<<<(E + 256 * K3_EPT - 1) / (256 * K3_EPT), 256, 0, stream>>>(
        srcv, dstv, bucketCursor, tmp, E);
    fine_scatter_kernel<<<nbuck, 256, 0, stream>>>(
        tmp, bucketBase, csr, offsets, counts, n);
    l1_edge_kernel<<<(n + 3) / 4, 256, 0, stream>>>(
        offsets, counts, csr, asrc1, adst1, h1, b1, W2, as2, ad2, h2, asrc2, adst2, n);
    l2_edge_kernel<<<(n + 3) / 4, 256, 0, stream>>>(
        offsets, counts, csr, asrc2, adst2, h2, b2, out, n);
}

// Round 15
// 161.724 us; speedup vs baseline: 1.4589x; 1.0728x over previous
//
#include <hip/hip_runtime.h>
#include <hip/hip_bf16.h>

#define IN_DIM 512
#define HEADS 8
#define HID 8
#define OUT_DIM 7
#define NEG_SLOPE 0.2f

typedef __attribute__((ext_vector_type(8))) short short8b;   // 8 bf16 (4 VGPR)
typedef __attribute__((ext_vector_type(4))) float f32x4;

#define BSHIFT 7
#define BMASK 127
#define K3_EPT 16

// ---------------- prep: W1 fragment-pack (blocks 0..127) || bucket hist (128..639)
__global__ __launch_bounds__(256) void prep_kernel(
    const float* __restrict__ W1, unsigned short* __restrict__ bhi,
    unsigned short* __restrict__ blo,
    const int* __restrict__ dst, int* __restrict__ bucketCounts, int E, int nbuck)
{
    __shared__ int cnt[512];
    int t = threadIdx.x;
    if (blockIdx.x < 128) {
        // pack: i = k-frag-major index; see w1_pack derivation (round 11)
        int i = blockIdx.x * 256 + t;       // 0..32767
        int j = i & 7;
        int lane = (i >> 3) & 63;
        int T = (i >> 9) & 3;
        int chunk = i >> 11;
        int col = 16 * T + (lane & 15);
        int k = chunk * 32 + 8 * (lane >> 4) + j;
        float w = W1[k * 64 + col];
        unsigned u = __float_as_uint(w);
        unsigned hu = u & 0xFFFF0000u;
        float rem = w - __uint_as_float(hu);
        bhi[i] = (unsigned short)(hu >> 16);
        blo[i] = (unsigned short)(__float_as_uint(rem) >> 16);
    } else {
        int b = blockIdx.x - 128;           // 0..511
        cnt[t] = 0; cnt[t + 256] = 0;
        __syncthreads();
        int i = b * 256 + t;
        int stride = 512 * 256;
        for (; i < E; i += stride) atomicAdd(&cnt[dst[i] >> BSHIFT], 1);
        __syncthreads();
        if (t < nbuck && cnt[t]) atomicAdd(&bucketCounts[t], cnt[t]);
        int t2 = t + 256;
        if (t2 < nbuck && cnt[t2]) atomicAdd(&bucketCounts[t2], cnt[t2]);
    }
}

__global__ __launch_bounds__(512) void bucket_scan_kernel(
    const int* __restrict__ bucketCounts, int* __restrict__ bucketBase,
    int* __restrict__ bucketCursor, int nbuck)
{
    __shared__ int wsum[8];
    int t = threadIdx.x, lane = t & 63, w = t >> 6;
    int c = (t < nbuck) ? bucketCounts[t] : 0;
    int inc = c;
    #pragma unroll
    for (int d = 1; d < 64; d <<= 1) {
        int u = __shfl_up(inc, d);
        if (lane >= d) inc += u;
    }
    if (lane == 63) wsum[w] = inc;
    __syncthreads();
    if (t == 0) { int run = 0; for (int k = 0; k < 8; ++k) { int tmp = wsum[k]; wsum[k] = run; run += tmp; } }
    __syncthreads();
    int excl = inc - c + wsum[w];
    if (t < nbuck) { bucketBase[t] = excl; bucketCursor[t] = excl; }
    if (t == nbuck) bucketBase[t] = excl;
}

// ---------------- fused: coarse scatter (blocks 0..nCoarse-1) || GEMM1 (rest)
// Coarse reuses gemm1's LDS block (4 KB of the 33.8 KB).
__global__ __launch_bounds__(256) void gemm1_coarse_kernel(
    const float* __restrict__ x,
    const unsigned short* __restrict__ bhi, const unsigned short* __restrict__ blo,
    const float* __restrict__ as1, const float* __restrict__ ad1,
    float* __restrict__ h1, float* __restrict__ asrc1, float* __restrict__ adst1,
    int n,
    const int* __restrict__ src, const int* __restrict__ dstv,
    int* __restrict__ bucketCursor, unsigned int* __restrict__ tmp, int E, int nCoarse)
{
    __shared__ float lds[4][16][132];   // gemm1 stage/partials; coarse reuses as cnt/gbase
    int t = threadIdx.x;

    if ((int)blockIdx.x < nCoarse) {
        // ---- coarse scatter part ----
        int* cnt   = (int*)&lds[0][0][0];
        int* gbase = cnt + 512;
        cnt[t] = 0; cnt[t + 256] = 0;
        __syncthreads();
        int base = blockIdx.x * (256 * K3_EPT);
        unsigned int pk[K3_EPT];
        unsigned int meta[K3_EPT];
        #pragma unroll
        for (int j = 0; j < K3_EPT; ++j) {
            int i = base + t + j * 256;
            if (i < E) {
                int d = dstv[i], s = src[i];
                int b = d >> BSHIFT;
                pk[j] = ((unsigned)s << 16) | (unsigned)(d & BMASK);
                int r = atomicAdd(&cnt[b], 1);
                meta[j] = ((unsigned)r << 9) | (unsigned)b;
            } else {
                meta[j] = 0xFFFFFFFFu; pk[j] = 0;
            }
        }
        __syncthreads();
        if (cnt[t] > 0) gbase[t] = atomicAdd(&bucketCursor[t], cnt[t]);
        int t2 = t + 256;
        if (cnt[t2] > 0) gbase[t2] = atomicAdd(&bucketCursor[t2], cnt[t2]);
        __syncthreads();
        #pragma unroll
        for (int j = 0; j < K3_EPT; ++j) {
            if (meta[j] != 0xFFFFFFFFu) {
                int b = meta[j] & 511;
                int r = meta[j] >> 9;
                tmp[gbase[b] + r] = pk[j];
            }
        }
        return;
    }

    // ---- GEMM1 part ----
    int wave = t >> 6, l = t & 63;
    int il = l & 15, g = l >> 4;
    int r0 = (blockIdx.x - nCoarse) * 16;
    int kw = wave * 128;

    #pragma unroll
    for (int j = 0; j < 8; ++j) {
        int idx = j * 64 + l;          // 0..511
        int row = idx >> 5;
        int kq = idx & 31;
        int gr = r0 + row; if (gr >= n) gr = n - 1;
        float4 v = *(const float4*)(x + (size_t)gr * IN_DIM + kw + kq * 4);
        *(float4*)(&lds[wave][row][kq * 4]) = v;
    }

    f32x4 acc[4] = {{0.f,0.f,0.f,0.f},{0.f,0.f,0.f,0.f},{0.f,0.f,0.f,0.f},{0.f,0.f,0.f,0.f}};

    #pragma unroll
    for (int it = 0; it < 4; ++it) {
        float av[8];
        *(float4*)(&av[0]) = *(const float4*)(&lds[wave][il][32 * it + 8 * g]);
        *(float4*)(&av[4]) = *(const float4*)(&lds[wave][il][32 * it + 8 * g + 4]);
        short8b Ahi, Alo;
        #pragma unroll
        for (int j = 0; j < 8; ++j) {
            unsigned u = __float_as_uint(av[j]);
            unsigned hu = u & 0xFFFF0000u;
            float rem = av[j] - __uint_as_float(hu);
            Ahi[j] = (short)(hu >> 16);
            Alo[j] = (short)(__float_as_uint(rem) >> 16);
        }
        int chunk = wave * 4 + it;
        const short8b* bh = (const short8b*)bhi + (size_t)(chunk * 4) * 64 + l;
        const short8b* bl = (const short8b*)blo + (size_t)(chunk * 4) * 64 + l;
        short8b Bh[4], Bl[4];
        #pragma unroll
        for (int T = 0; T < 4; ++T) { Bh[T] = bh[T * 64]; Bl[T] = bl[T * 64]; }
        #pragma unroll
        for (int T = 0; T < 4; ++T) {
            acc[T] = __builtin_amdgcn_mfma_f32_16x16x32_bf16(Alo, Bh[T], acc[T], 0, 0, 0);
            acc[T] = __builtin_amdgcn_mfma_f32_16x16x32_bf16(Ahi, Bl[T], acc[T], 0, 0, 0);
            acc[T] = __builtin_amdgcn_mfma_f32_16x16x32_bf16(Ahi, Bh[T], acc[T], 0, 0, 0);
        }
    }

    #pragma unroll
    for (int T = 0; T < 4; ++T)
        #pragma unroll
        for (int r = 0; r < 4; ++r)
            lds[wave][4 * g + r][16 * T + il] = acc[T][r];
    __syncthreads();

    int row = t >> 4, c0 = (t & 15) * 4;
    int grow = r0 + row;
    float v0 = lds[0][row][c0]     + lds[1][row][c0]     + lds[2][row][c0]     + lds[3][row][c0];
    float v1 = lds[0][row][c0 + 1] + lds[1][row][c0 + 1] + lds[2][row][c0 + 1] + lds[3][row][c0 + 1];
    float v2 = lds[0][row][c0 + 2] + lds[1][row][c0 + 2] + lds[2][row][c0 + 2] + lds[3][row][c0 + 2];
    float v3 = lds[0][row][c0 + 3] + lds[1][row][c0 + 3] + lds[2][row][c0 + 3] + lds[3][row][c0 + 3];
    if (grow < n) {
        *(float4*)(h1 + (size_t)grow * 64 + c0) = make_float4(v0, v1, v2, v3);
        float4 asv = *(const float4*)(as1 + c0);
        float4 adv = *(const float4*)(ad1 + c0);
        float pa = v0 * asv.x + v1 * asv.y + v2 * asv.z + v3 * asv.w;
        float pd = v0 * adv.x + v1 * adv.y + v2 * adv.z + v3 * adv.w;
        pa += __shfl_xor(pa, 1);
        pd += __shfl_xor(pd, 1);
        if ((t & 1) == 0) {
            int head = (t & 15) >> 1;
            asrc1[grow * 8 + head] = pa;
            adst1[grow * 8 + head] = pd;
        }
    }
}

__global__ __launch_bounds__(256) void fine_scatter_kernel(
    const unsigned int* __restrict__ tmp, const int* __restrict__ bucketBase,
    int* __restrict__ csr, int* __restrict__ offsets, int* __restrict__ counts, int n)
{
    __shared__ int cnt[128];
    __shared__ int cur[128];
    __shared__ int wsum[2];
    int b = blockIdx.x;
    int t = threadIdx.x, lane = t & 63, w = t >> 6;
    int beg = bucketBase[b], end = bucketBase[b + 1];
    if (t < 128) cnt[t] = 0;
    __syncthreads();
    for (int i = beg + t; i < end; i += 256)
        atomicAdd(&cnt[tmp[i] & BMASK], 1);
    __syncthreads();
    if (t < 128) {
        int c = cnt[t];
        int inc = c;
        #pragma unroll
        for (int d = 1; d < 64; d <<= 1) {
            int u = __shfl_up(inc, d);
            if (lane >= d) inc += u;
        }
        if (lane == 63) wsum[w] = inc;
        __syncthreads();
        if (t == 0) { int r0_ = wsum[0]; wsum[0] = 0; wsum[1] = r0_; }
        __syncthreads();
        int excl = inc - c + wsum[w];
        int node = b * 128 + t;
        if (node < n) { offsets[node] = beg + excl; counts[node] = c; }
        cur[t] = excl;
    } else {
        __syncthreads(); __syncthreads();
    }
    __syncthreads();
    for (int i = beg + t; i < end; i += 256) {
        unsigned int p = tmp[i];
        int r = atomicAdd(&cur[p & BMASK], 1);
        csr[beg + r] = (int)(p >> 16);
    }
}

// ---------------- Layer-1 edge kernel: single-pass, LDS csr stage + deep MLP
__global__ __launch_bounds__(256) void l1_edge_kernel(
    const int* __restrict__ offsets, const int* __restrict__ counts,
    const int* __restrict__ csr,
    const float* __restrict__ asrc1, const float* __restrict__ adst1,
    const float* __restrict__ h1, const float* __restrict__ b1,
    const float* __restrict__ W2, const float* __restrict__ as2,
    const float* __restrict__ ad2,
    float* __restrict__ h2, float* __restrict__ asrc2, float* __restrict__ adst2,
    int n)
{
    __shared__ float w2t[8][64];
    __shared__ float s_as2[8], s_ad2[8], s_b1[64];
    __shared__ int csr_s[4][64];
    int t = threadIdx.x;
    if (t < 64) {
        #pragma unroll
        for (int j = 0; j < OUT_DIM; ++j) w2t[j][t] = W2[t * OUT_DIM + j];
        s_b1[t] = b1[t];
        if (t < OUT_DIM) { s_as2[t] = as2[t]; s_ad2[t] = ad2[t]; }
    }
    __syncthreads();

    int lane = t & 63;
    int nl = t >> 6;
    int node = blockIdx.x * 4 + nl;
    if (node >= n) return;
    int beg = offsets[node];
    int deg = counts[node];
    int q = lane >> 4;
    int il = lane & 15;
    int c0 = il * 4;
    int head = il >> 1;
    float adv = adst1[node * 8 + head];

    if (lane < deg) csr_s[nl][lane] = csr[beg + lane];
    int deg_r = deg < 64 ? deg : 64;
    const int* cs = &csr_s[nl][0];

    float4 acc = make_float4(0.f, 0.f, 0.f, 0.f);
    float ssum = 0.f;
    if (q == 0) {   // self loop
        float e = asrc1[node * 8 + head] + adv;
        e = e > 0.f ? e : NEG_SLOPE * e;
        float p = __expf(e);
        float4 hv = *(const float4*)(h1 + (size_t)node * 64 + c0);
        acc.x = p * hv.x; acc.y = p * hv.y; acc.z = p * hv.z; acc.w = p * hv.w;
        ssum = p;
    }
    int j = q;
    for (; j + 12 < deg_r; j += 16) {
        int s0 = cs[j];
        int s1 = cs[j + 4];
        int s2 = cs[j + 8];
        int s3 = cs[j + 12];
        float a0 = asrc1[s0 * 8 + head], a1 = asrc1[s1 * 8 + head];
        float a2 = asrc1[s2 * 8 + head], a3 = asrc1[s3 * 8 + head];
        float4 g0 = *(const float4*)(h1 + (size_t)s0 * 64 + c0);
        float4 g1 = *(const float4*)(h1 + (size_t)s1 * 64 + c0);
        float4 g2 = *(const float4*)(h1 + (size_t)s2 * 64 + c0);
        float4 g3 = *(const float4*)(h1 + (size_t)s3 * 64 + c0);
        float e0 = a0 + adv; e0 = e0 > 0.f ? e0 : NEG_SLOPE * e0;
        float e1 = a1 + adv; e1 = e1 > 0.f ? e1 : NEG_SLOPE * e1;
        float e2 = a2 + adv; e2 = e2 > 0.f ? e2 : NEG_SLOPE * e2;
        float e3 = a3 + adv; e3 = e3 > 0.f ? e3 : NEG_SLOPE * e3;
        float p0 = __expf(e0), p1 = __expf(e1);
        float p2 = __expf(e2), p3 = __expf(e3);
        acc.x = fmaf(p0, g0.x, acc.x); acc.y = fmaf(p0, g0.y, acc.y);
        acc.z = fmaf(p0, g0.z, acc.z); acc.w = fmaf(p0, g0.w, acc.w);
        acc.x = fmaf(p1, g1.x, acc.x); acc.y = fmaf(p1, g1.y, acc.y);
        acc.z = fmaf(p1, g1.z, acc.z); acc.w = fmaf(p1, g1.w, acc.w);
        acc.x = fmaf(p2, g2.x, acc.x); acc.y = fmaf(p2, g2.y, acc.y);
        acc.z = fmaf(p2, g2.z, acc.z); acc.w = fmaf(p2, g2.w, acc.w);
        acc.x = fmaf(p3, g3.x, acc.x); acc.y = fmaf(p3, g3.y, acc.y);
        acc.z = fmaf(p3, g3.z, acc.z); acc.w = fmaf(p3, g3.w, acc.w);
        ssum += (p0 + p1) + (p2 + p3);
    }
    for (; j < deg_r; j += 4) {
        int sn = cs[j];
        float a = asrc1[sn * 8 + head];
        float4 g = *(const float4*)(h1 + (size_t)sn * 64 + c0);
        float e = a + adv; e = e > 0.f ? e : NEG_SLOPE * e;
        float p = __expf(e);
        acc.x = fmaf(p, g.x, acc.x); acc.y = fmaf(p, g.y, acc.y);
        acc.z = fmaf(p, g.z, acc.z); acc.w = fmaf(p, g.w, acc.w);
        ssum += p;
    }
    for (; j < deg; j += 4) {
        int sn = csr[beg + j];
        float a = asrc1[sn * 8 + head];
        float4 g = *(const float4*)(h1 + (size_t)sn * 64 + c0);
        float e = a + adv; e = e > 0.f ? e : NEG_SLOPE * e;
        float p = __expf(e);
        acc.x = fmaf(p, g.x, acc.x); acc.y = fmaf(p, g.y, acc.y);
        acc.z = fmaf(p, g.z, acc.z); acc.w = fmaf(p, g.w, acc.w);
        ssum += p;
    }
    acc.x += __shfl_xor(acc.x, 16); acc.x += __shfl_xor(acc.x, 32);
    acc.y += __shfl_xor(acc.y, 16); acc.y += __shfl_xor(acc.y, 32);
    acc.z += __shfl_xor(acc.z, 16); acc.z += __shfl_xor(acc.z, 32);
    acc.w += __shfl_xor(acc.w, 16); acc.w += __shfl_xor(acc.w, 32);
    ssum  += __shfl_xor(ssum, 16);  ssum  += __shfl_xor(ssum, 32);
    float inv = 1.f / fmaxf(ssum, 1e-16f);

    float4 bv = *(const float4*)(&s_b1[c0]);
    float v0 = acc.x * inv + bv.x;
    float v1 = acc.y * inv + bv.y;
    float v2 = acc.z * inv + bv.z;
    float v3 = acc.w * inv + bv.w;
    v0 = v0 > 0.f ? v0 : __expf(v0) - 1.f;
    v1 = v1 > 0.f ? v1 : __expf(v1) - 1.f;
    v2 = v2 > 0.f ? v2 : __expf(v2) - 1.f;
    v3 = v3 > 0.f ? v3 : __expf(v3) - 1.f;

    float hj[OUT_DIM];
    #pragma unroll
    for (int jj = 0; jj < OUT_DIM; ++jj) {
        float4 wv = *(const float4*)(&w2t[jj][c0]);
        float p = v0 * wv.x + v1 * wv.y + v2 * wv.z + v3 * wv.w;
        p += __shfl_xor(p, 1);
        p += __shfl_xor(p, 2);
        p += __shfl_xor(p, 4);
        p += __shfl_xor(p, 8);
        hj[jj] = p;
    }
    float a_s = 0.f, a_d = 0.f;
    #pragma unroll
    for (int jj = 0; jj < OUT_DIM; ++jj) { a_s += hj[jj] * s_as2[jj]; a_d += hj[jj] * s_ad2[jj]; }
    if (lane < 8) h2[node * 8 + lane] = (lane < OUT_DIM) ? hj[lane] : 0.f;
    if (lane == 0) { asrc2[node] = a_s; adst2[node] = a_d; }
}

// ---------------- Layer-2 edge kernel: single-pass -> final logits --------
__global__ __launch_bounds__(256) void l2_edge_kernel(
    const int* __restrict__ offsets, const int* __restrict__ counts,
    const int* __restrict__ csr,
    const float* __restrict__ asrc2, const float* __restrict__ adst2,
    const float* __restrict__ h2, const float* __restrict__ b2,
    float* __restrict__ out, int n)
{
    int t = threadIdx.x, lane = t & 63;
    int node = blockIdx.x * 4 + (t >> 6);
    if (node >= n) return;
    int beg = offsets[node];
    int deg = counts[node];
    float adv = adst2[node];

    int c = lane & 7, slot = lane >> 3;
    float acc = 0.f, ssum = 0.f;
    if (slot == 0) {
        float e = asrc2[node] + adv;
        e = e > 0.f ? e : NEG_SLOPE * e;
        float p = __expf(e);
        acc = p * h2[node * 8 + c];
        ssum = p;
    }
    int j = slot;
    for (; j + 8 < deg; j += 16) {
        int s0 = csr[beg + j], s1 = csr[beg + j + 8];
        float a0 = asrc2[s0], a1 = asrc2[s1];
        float g0 = h2[s0 * 8 + c], g1 = h2[s1 * 8 + c];
        float e0 = a0 + adv; e0 = e0 > 0.f ? e0 : NEG_SLOPE * e0;
        float e1 = a1 + adv; e1 = e1 > 0.f ? e1 : NEG_SLOPE * e1;
        float p0 = __expf(e0), p1 = __expf(e1);
        acc = fmaf(p0, g0, acc); acc = fmaf(p1, g1, acc);
        ssum += p0 + p1;
    }
    for (; j < deg; j += 8) {
        int sn = csr[beg + j];
        float e = asrc2[sn] + adv;
        e = e > 0.f ? e : NEG_SLOPE * e;
        float p = __expf(e);
        acc = fmaf(p, h2[sn * 8 + c], acc);
        ssum += p;
    }
    acc  += __shfl_xor(acc, 8);  acc  += __shfl_xor(acc, 16);  acc  += __shfl_xor(acc, 32);
    ssum += __shfl_xor(ssum, 8); ssum += __shfl_xor(ssum, 16); ssum += __shfl_xor(ssum, 32);
    float inv = 1.f / fmaxf(ssum, 1e-16f);
    if (lane < OUT_DIM) out[(size_t)node * OUT_DIM + lane] = acc * inv + b2[lane];
}

// ---------------- launch ----------------
static inline size_t rup256(size_t x) { return (x + 255) & ~(size_t)255; }

extern "C" void kernel_launch(void* const* d_in, const int* in_sizes, int n_in,
                              void* d_out, int out_size, void* d_ws, size_t ws_size,
                              hipStream_t stream)
{
    int n = in_sizes[0] / IN_DIM;       // 50000
    int E = in_sizes[1] / 2;            // 1600000
    int nbuck = (n + BMASK) >> BSHIFT;  // 391
    int nCoarse = (E + 256 * K3_EPT - 1) / (256 * K3_EPT);   // 391

    const float* x   = (const float*)d_in[0];
    const int*   ei  = (const int*)d_in[1];
    const int*   srcv = ei;
    const int*   dstv = ei + E;
    const float* W1  = (const float*)d_in[2];
    const float* as1 = (const float*)d_in[3];
    const float* ad1 = (const float*)d_in[4];
    const float* b1  = (const float*)d_in[5];
    const float* W2  = (const float*)d_in[6];
    const float* as2 = (const float*)d_in[7];
    const float* ad2 = (const float*)d_in[8];
    const float* b2  = (const float*)d_in[9];
    float* out = (float*)d_out;

    char* p = (char*)d_ws;
    auto alloc = [&](size_t bytes) { char* q = p; p += rup256(bytes); return (void*)q; };
    float* h1      = (float*)alloc((size_t)n * 64 * 4);
    float* asrc1   = (float*)alloc((size_t)n * 8 * 4);
    float* adst1   = (float*)alloc((size_t)n * 8 * 4);
    float* h2      = (float*)alloc((size_t)n * 8 * 4);
    float* asrc2   = (float*)alloc((size_t)n * 4);
    float* adst2   = (float*)alloc((size_t)n * 4);
    int*   counts  = (int*)alloc((size_t)n * 4);
    int*   offsets = (int*)alloc(((size_t)n + 1) * 4);
    int*   csr     = (int*)alloc((size_t)E * 4);
    unsigned int* tmp = (unsigned int*)alloc((size_t)E * 4);
    int*   bucketCounts = (int*)alloc(512 * 4);
    int*   bucketBase   = (int*)alloc(513 * 4);
    int*   bucketCursor = (int*)alloc(512 * 4);
    unsigned short* bhi = (unsigned short*)alloc((size_t)IN_DIM * 64 * 2);
    unsigned short* blo = (unsigned short*)alloc((size_t)IN_DIM * 64 * 2);

    hipMemsetAsync(bucketCounts, 0, 512 * 4, stream);
    // pack || hist
    prep_kernel<<<128 + 512, 256, 0, stream>>>(W1, bhi, blo, dstv, bucketCounts, E, nbuck);
    bucket_scan_kernel<<<1, 512, 0, stream>>>(bucketCounts, bucketBase, bucketCursor, nbuck);
    // coarse (blocks 0..390, early dispatch) || gemm1 (rest)
    gemm1_coarse_kernel<<<nCoarse + (n + 15) / 16, 256, 0, stream>>>(
        x, bhi, blo, as1, ad1, h1, asrc1, adst1, n,
        srcv, dstv, bucketCursor, tmp, E, nCoarse);
    fine_scatter_kernel<<<nbuck, 256, 0, stream>>>(
        tmp, bucketBase, csr, offsets, counts, n);
    l1_edge_kernel<<<(n + 3) / 4, 256, 0, stream>>>(
        offsets, counts, csr, asrc1, adst1, h1, b1, W2, as2, ad2, h2, asrc2, adst2, n);
    l2_edge_kernel<<<(n + 3) / 4, 256, 0, stream>>>(
        offsets, counts, csr, asrc2, adst2, h2, b2, out, n);
}

// Round 16
// 143.633 us; speedup vs baseline: 1.6427x; 1.1259x over previous
//
#include <hip/hip_runtime.h>
#include <hip/hip_bf16.h>

#define IN_DIM 512
#define HEADS 8
#define HID 8
#define OUT_DIM 7
#define NEG_SLOPE 0.2f

typedef __attribute__((ext_vector_type(8))) short short8b;   // 8 bf16 (4 VGPR)
typedef __attribute__((ext_vector_type(4))) float f32x4;

#define BSHIFT 7
#define BMASK 127
#define K3_EPT 16

__device__ __forceinline__ unsigned short f2bf_rne(float f) {
    unsigned u = __float_as_uint(f);
    unsigned r = (u + 0x7FFFu + ((u >> 16) & 1u)) >> 16;
    return (unsigned short)r;
}
__device__ __forceinline__ float bf2f(unsigned short s) {
    return __uint_as_float((unsigned)s << 16);
}

// ---------------- prep: W1 fragment-pack (blocks 0..127) || bucket hist (128..639)
__global__ __launch_bounds__(256) void prep_kernel(
    const float* __restrict__ W1, unsigned short* __restrict__ bhi,
    unsigned short* __restrict__ blo,
    const int* __restrict__ dst, int* __restrict__ bucketCounts, int E, int nbuck)
{
    __shared__ int cnt[512];
    int t = threadIdx.x;
    if (blockIdx.x < 128) {
        int i = blockIdx.x * 256 + t;       // 0..32767
        int j = i & 7;
        int lane = (i >> 3) & 63;
        int T = (i >> 9) & 3;
        int chunk = i >> 11;
        int col = 16 * T + (lane & 15);
        int k = chunk * 32 + 8 * (lane >> 4) + j;
        float w = W1[k * 64 + col];
        unsigned u = __float_as_uint(w);
        unsigned hu = u & 0xFFFF0000u;
        float rem = w - __uint_as_float(hu);
        bhi[i] = (unsigned short)(hu >> 16);
        blo[i] = (unsigned short)(__float_as_uint(rem) >> 16);
    } else {
        int b = blockIdx.x - 128;           // 0..511
        cnt[t] = 0; cnt[t + 256] = 0;
        __syncthreads();
        int i = b * 256 + t;
        int stride = 512 * 256;
        for (; i < E; i += stride) atomicAdd(&cnt[dst[i] >> BSHIFT], 1);
        __syncthreads();
        if (t < nbuck && cnt[t]) atomicAdd(&bucketCounts[t], cnt[t]);
        int t2 = t + 256;
        if (t2 < nbuck && cnt[t2]) atomicAdd(&bucketCounts[t2], cnt[t2]);
    }
}

__global__ __launch_bounds__(512) void bucket_scan_kernel(
    const int* __restrict__ bucketCounts, int* __restrict__ bucketBase,
    int* __restrict__ bucketCursor, int nbuck)
{
    __shared__ int wsum[8];
    int t = threadIdx.x, lane = t & 63, w = t >> 6;
    int c = (t < nbuck) ? bucketCounts[t] : 0;
    int inc = c;
    #pragma unroll
    for (int d = 1; d < 64; d <<= 1) {
        int u = __shfl_up(inc, d);
        if (lane >= d) inc += u;
    }
    if (lane == 63) wsum[w] = inc;
    __syncthreads();
    if (t == 0) { int run = 0; for (int k = 0; k < 8; ++k) { int tmp = wsum[k]; wsum[k] = run; run += tmp; } }
    __syncthreads();
    int excl = inc - c + wsum[w];
    if (t < nbuck) { bucketBase[t] = excl; bucketCursor[t] = excl; }
    if (t == nbuck) bucketBase[t] = excl;
}

// ---------------- fused: coarse scatter (blocks 0..nCoarse-1) || GEMM1 (rest)
// h1 stored as bf16 (RNE) — halves l1's gather traffic.
__global__ __launch_bounds__(256) void gemm1_coarse_kernel(
    const float* __restrict__ x,
    const unsigned short* __restrict__ bhi, const unsigned short* __restrict__ blo,
    const float* __restrict__ as1, const float* __restrict__ ad1,
    unsigned short* __restrict__ h1, float* __restrict__ asrc1, float* __restrict__ adst1,
    int n,
    const int* __restrict__ src, const int* __restrict__ dstv,
    int* __restrict__ bucketCursor, unsigned int* __restrict__ tmp, int E, int nCoarse)
{
    __shared__ float lds[4][16][132];   // gemm1 stage/partials; coarse reuses as cnt/gbase
    int t = threadIdx.x;

    if ((int)blockIdx.x < nCoarse) {
        int* cnt   = (int*)&lds[0][0][0];
        int* gbase = cnt + 512;
        cnt[t] = 0; cnt[t + 256] = 0;
        __syncthreads();
        int base = blockIdx.x * (256 * K3_EPT);
        unsigned int pk[K3_EPT];
        unsigned int meta[K3_EPT];
        #pragma unroll
        for (int j = 0; j < K3_EPT; ++j) {
            int i = base + t + j * 256;
            if (i < E) {
                int d = dstv[i], s = src[i];
                int b = d >> BSHIFT;
                pk[j] = ((unsigned)s << 16) | (unsigned)(d & BMASK);
                int r = atomicAdd(&cnt[b], 1);
                meta[j] = ((unsigned)r << 9) | (unsigned)b;
            } else {
                meta[j] = 0xFFFFFFFFu; pk[j] = 0;
            }
        }
        __syncthreads();
        if (cnt[t] > 0) gbase[t] = atomicAdd(&bucketCursor[t], cnt[t]);
        int t2 = t + 256;
        if (cnt[t2] > 0) gbase[t2] = atomicAdd(&bucketCursor[t2], cnt[t2]);
        __syncthreads();
        #pragma unroll
        for (int j = 0; j < K3_EPT; ++j) {
            if (meta[j] != 0xFFFFFFFFu) {
                int b = meta[j] & 511;
                int r = meta[j] >> 9;
                tmp[gbase[b] + r] = pk[j];
            }
        }
        return;
    }

    // ---- GEMM1 part ----
    int wave = t >> 6, l = t & 63;
    int il = l & 15, g = l >> 4;
    int r0 = (blockIdx.x - nCoarse) * 16;
    int kw = wave * 128;

    #pragma unroll
    for (int j = 0; j < 8; ++j) {
        int idx = j * 64 + l;          // 0..511
        int row = idx >> 5;
        int kq = idx & 31;
        int gr = r0 + row; if (gr >= n) gr = n - 1;
        float4 v = *(const float4*)(x + (size_t)gr * IN_DIM + kw + kq * 4);
        *(float4*)(&lds[wave][row][kq * 4]) = v;
    }

    f32x4 acc[4] = {{0.f,0.f,0.f,0.f},{0.f,0.f,0.f,0.f},{0.f,0.f,0.f,0.f},{0.f,0.f,0.f,0.f}};

    #pragma unroll
    for (int it = 0; it < 4; ++it) {
        float av[8];
        *(float4*)(&av[0]) = *(const float4*)(&lds[wave][il][32 * it + 8 * g]);
        *(float4*)(&av[4]) = *(const float4*)(&lds[wave][il][32 * it + 8 * g + 4]);
        short8b Ahi, Alo;
        #pragma unroll
        for (int j = 0; j < 8; ++j) {
            unsigned u = __float_as_uint(av[j]);
            unsigned hu = u & 0xFFFF0000u;
            float rem = av[j] - __uint_as_float(hu);
            Ahi[j] = (short)(hu >> 16);
            Alo[j] = (short)(__float_as_uint(rem) >> 16);
        }
        int chunk = wave * 4 + it;
        const short8b* bh = (const short8b*)bhi + (size_t)(chunk * 4) * 64 + l;
        const short8b* bl = (const short8b*)blo + (size_t)(chunk * 4) * 64 + l;
        short8b Bh[4], Bl[4];
        #pragma unroll
        for (int T = 0; T < 4; ++T) { Bh[T] = bh[T * 64]; Bl[T] = bl[T * 64]; }
        #pragma unroll
        for (int T = 0; T < 4; ++T) {
            acc[T] = __builtin_amdgcn_mfma_f32_16x16x32_bf16(Alo, Bh[T], acc[T], 0, 0, 0);
            acc[T] = __builtin_amdgcn_mfma_f32_16x16x32_bf16(Ahi, Bl[T], acc[T], 0, 0, 0);
            acc[T] = __builtin_amdgcn_mfma_f32_16x16x32_bf16(Ahi, Bh[T], acc[T], 0, 0, 0);
        }
    }

    #pragma unroll
    for (int T = 0; T < 4; ++T)
        #pragma unroll
        for (int r = 0; r < 4; ++r)
            lds[wave][4 * g + r][16 * T + il] = acc[T][r];
    __syncthreads();

    int row = t >> 4, c0 = (t & 15) * 4;
    int grow = r0 + row;
    float v0 = lds[0][row][c0]     + lds[1][row][c0]     + lds[2][row][c0]     + lds[3][row][c0];
    float v1 = lds[0][row][c0 + 1] + lds[1][row][c0 + 1] + lds[2][row][c0 + 1] + lds[3][row][c0 + 1];
    float v2 = lds[0][row][c0 + 2] + lds[1][row][c0 + 2] + lds[2][row][c0 + 2] + lds[3][row][c0 + 2];
    float v3 = lds[0][row][c0 + 3] + lds[1][row][c0 + 3] + lds[2][row][c0 + 3] + lds[3][row][c0 + 3];
    if (grow < n) {
        ushort4 hb;
        hb.x = f2bf_rne(v0); hb.y = f2bf_rne(v1);
        hb.z = f2bf_rne(v2); hb.w = f2bf_rne(v3);
        *(ushort4*)(h1 + (size_t)grow * 64 + c0) = hb;
        float4 asv = *(const float4*)(as1 + c0);
        float4 adv = *(const float4*)(ad1 + c0);
        float pa = v0 * asv.x + v1 * asv.y + v2 * asv.z + v3 * asv.w;
        float pd = v0 * adv.x + v1 * adv.y + v2 * adv.z + v3 * adv.w;
        pa += __shfl_xor(pa, 1);
        pd += __shfl_xor(pd, 1);
        if ((t & 1) == 0) {
            int head = (t & 15) >> 1;
            asrc1[grow * 8 + head] = pa;
            adst1[grow * 8 + head] = pd;
        }
    }
}

__global__ __launch_bounds__(256) void fine_scatter_kernel(
    const unsigned int* __restrict__ tmp, const int* __restrict__ bucketBase,
    int* __restrict__ csr, int* __restrict__ offsets, int* __restrict__ counts, int n)
{
    __shared__ int cnt[128];
    __shared__ int cur[128];
    __shared__ int wsum[2];
    int b = blockIdx.x;
    int t = threadIdx.x, lane = t & 63, w = t >> 6;
    int beg = bucketBase[b], end = bucketBase[b + 1];
    if (t < 128) cnt[t] = 0;
    __syncthreads();
    for (int i = beg + t; i < end; i += 256)
        atomicAdd(&cnt[tmp[i] & BMASK], 1);
    __syncthreads();
    if (t < 128) {
        int c = cnt[t];
        int inc = c;
        #pragma unroll
        for (int d = 1; d < 64; d <<= 1) {
            int u = __shfl_up(inc, d);
            if (lane >= d) inc += u;
        }
        if (lane == 63) wsum[w] = inc;
        __syncthreads();
        if (t == 0) { int r0_ = wsum[0]; wsum[0] = 0; wsum[1] = r0_; }
        __syncthreads();
        int excl = inc - c + wsum[w];
        int node = b * 128 + t;
        if (node < n) { offsets[node] = beg + excl; counts[node] = c; }
        cur[t] = excl;
    } else {
        __syncthreads(); __syncthreads();
    }
    __syncthreads();
    for (int i = beg + t; i < end; i += 256) {
        unsigned int p = tmp[i];
        int r = atomicAdd(&cur[p & BMASK], 1);
        csr[beg + r] = (int)(p >> 16);
    }
}

// ---------------- Layer-1 edge kernel: single-pass, bf16 h1 gathers --------
__global__ __launch_bounds__(256) void l1_edge_kernel(
    const int* __restrict__ offsets, const int* __restrict__ counts,
    const int* __restrict__ csr,
    const float* __restrict__ asrc1, const float* __restrict__ adst1,
    const unsigned short* __restrict__ h1, const float* __restrict__ b1,
    const float* __restrict__ W2, const float* __restrict__ as2,
    const float* __restrict__ ad2,
    float* __restrict__ h2, float* __restrict__ asrc2, float* __restrict__ adst2,
    int n)
{
    __shared__ float w2t[8][64];
    __shared__ float s_as2[8], s_ad2[8], s_b1[64];
    __shared__ int csr_s[4][64];
    int t = threadIdx.x;
    if (t < 64) {
        #pragma unroll
        for (int j = 0; j < OUT_DIM; ++j) w2t[j][t] = W2[t * OUT_DIM + j];
        s_b1[t] = b1[t];
        if (t < OUT_DIM) { s_as2[t] = as2[t]; s_ad2[t] = ad2[t]; }
    }
    __syncthreads();

    int lane = t & 63;
    int nl = t >> 6;
    int node = blockIdx.x * 4 + nl;
    if (node >= n) return;
    int beg = offsets[node];
    int deg = counts[node];
    int q = lane >> 4;
    int il = lane & 15;
    int c0 = il * 4;
    int head = il >> 1;
    float adv = adst1[node * 8 + head];

    if (lane < deg) csr_s[nl][lane] = csr[beg + lane];
    int deg_r = deg < 64 ? deg : 64;
    const int* cs = &csr_s[nl][0];

    float4 acc = make_float4(0.f, 0.f, 0.f, 0.f);
    float ssum = 0.f;
    if (q == 0) {   // self loop
        float e = asrc1[node * 8 + head] + adv;
        e = e > 0.f ? e : NEG_SLOPE * e;
        float p = __expf(e);
        ushort4 hu = *(const ushort4*)(h1 + (size_t)node * 64 + c0);
        acc.x = p * bf2f(hu.x); acc.y = p * bf2f(hu.y);
        acc.z = p * bf2f(hu.z); acc.w = p * bf2f(hu.w);
        ssum = p;
    }
    int j = q;
    for (; j + 12 < deg_r; j += 16) {
        int s0 = cs[j];
        int s1 = cs[j + 4];
        int s2 = cs[j + 8];
        int s3 = cs[j + 12];
        float a0 = asrc1[s0 * 8 + head], a1 = asrc1[s1 * 8 + head];
        float a2 = asrc1[s2 * 8 + head], a3 = asrc1[s3 * 8 + head];
        ushort4 g0 = *(const ushort4*)(h1 + (size_t)s0 * 64 + c0);
        ushort4 g1 = *(const ushort4*)(h1 + (size_t)s1 * 64 + c0);
        ushort4 g2 = *(const ushort4*)(h1 + (size_t)s2 * 64 + c0);
        ushort4 g3 = *(const ushort4*)(h1 + (size_t)s3 * 64 + c0);
        float e0 = a0 + adv; e0 = e0 > 0.f ? e0 : NEG_SLOPE * e0;
        float e1 = a1 + adv; e1 = e1 > 0.f ? e1 : NEG_SLOPE * e1;
        float e2 = a2 + adv; e2 = e2 > 0.f ? e2 : NEG_SLOPE * e2;
        float e3 = a3 + adv; e3 = e3 > 0.f ? e3 : NEG_SLOPE * e3;
        float p0 = __expf(e0), p1 = __expf(e1);
        float p2 = __expf(e2), p3 = __expf(e3);
        acc.x = fmaf(p0, bf2f(g0.x), acc.x); acc.y = fmaf(p0, bf2f(g0.y), acc.y);
        acc.z = fmaf(p0, bf2f(g0.z), acc.z); acc.w = fmaf(p0, bf2f(g0.w), acc.w);
        acc.x = fmaf(p1, bf2f(g1.x), acc.x); acc.y = fmaf(p1, bf2f(g1.y), acc.y);
        acc.z = fmaf(p1, bf2f(g1.z), acc.z); acc.w = fmaf(p1, bf2f(g1.w), acc.w);
        acc.x = fmaf(p2, bf2f(g2.x), acc.x); acc.y = fmaf(p2, bf2f(g2.y), acc.y);
        acc.z = fmaf(p2, bf2f(g2.z), acc.z); acc.w = fmaf(p2, bf2f(g2.w), acc.w);
        acc.x = fmaf(p3, bf2f(g3.x), acc.x); acc.y = fmaf(p3, bf2f(g3.y), acc.y);
        acc.z = fmaf(p3, bf2f(g3.z), acc.z); acc.w = fmaf(p3, bf2f(g3.w), acc.w);
        ssum += (p0 + p1) + (p2 + p3);
    }
    for (; j < deg_r; j += 4) {
        int sn = cs[j];
        float a = asrc1[sn * 8 + head];
        ushort4 g = *(const ushort4*)(h1 + (size_t)sn * 64 + c0);
        float e = a + adv; e = e > 0.f ? e : NEG_SLOPE * e;
        float p = __expf(e);
        acc.x = fmaf(p, bf2f(g.x), acc.x); acc.y = fmaf(p, bf2f(g.y), acc.y);
        acc.z = fmaf(p, bf2f(g.z), acc.z); acc.w = fmaf(p, bf2f(g.w), acc.w);
        ssum += p;
    }
    for (; j < deg; j += 4) {
        int sn = csr[beg + j];
        float a = asrc1[sn * 8 + head];
        ushort4 g = *(const ushort4*)(h1 + (size_t)sn * 64 + c0);
        float e = a + adv; e = e > 0.f ? e : NEG_SLOPE * e;
        float p = __expf(e);
        acc.x = fmaf(p, bf2f(g.x), acc.x); acc.y = fmaf(p, bf2f(g.y), acc.y);
        acc.z = fmaf(p, bf2f(g.z), acc.z); acc.w = fmaf(p, bf2f(g.w), acc.w);
        ssum += p;
    }
    acc.x += __shfl_xor(acc.x, 16); acc.x += __shfl_xor(acc.x, 32);
    acc.y += __shfl_xor(acc.y, 16); acc.y += __shfl_xor(acc.y, 32);
    acc.z += __shfl_xor(acc.z, 16); acc.z += __shfl_xor(acc.z, 32);
    acc.w += __shfl_xor(acc.w, 16); acc.w += __shfl_xor(acc.w, 32);
    ssum  += __shfl_xor(ssum, 16);  ssum  += __shfl_xor(ssum, 32);
    float inv = 1.f / fmaxf(ssum, 1e-16f);

    float4 bv = *(const float4*)(&s_b1[c0]);
    float v0 = acc.x * inv + bv.x;
    float v1 = acc.y * inv + bv.y;
    float v2 = acc.z * inv + bv.z;
    float v3 = acc.w * inv + bv.w;
    v0 = v0 > 0.f ? v0 : __expf(v0) - 1.f;
    v1 = v1 > 0.f ? v1 : __expf(v1) - 1.f;
    v2 = v2 > 0.f ? v2 : __expf(v2) - 1.f;
    v3 = v3 > 0.f ? v3 : __expf(v3) - 1.f;

    float hj[OUT_DIM];
    #pragma unroll
    for (int jj = 0; jj < OUT_DIM; ++jj) {
        float4 wv = *(const float4*)(&w2t[jj][c0]);
        float p = v0 * wv.x + v1 * wv.y + v2 * wv.z + v3 * wv.w;
        p += __shfl_xor(p, 1);
        p += __shfl_xor(p, 2);
        p += __shfl_xor(p, 4);
        p += __shfl_xor(p, 8);
        hj[jj] = p;
    }
    float a_s = 0.f, a_d = 0.f;
    #pragma unroll
    for (int jj = 0; jj < OUT_DIM; ++jj) { a_s += hj[jj] * s_as2[jj]; a_d += hj[jj] * s_ad2[jj]; }
    if (lane < 8) h2[node * 8 + lane] = (lane < OUT_DIM) ? hj[lane] : 0.f;
    if (lane == 0) { asrc2[node] = a_s; adst2[node] = a_d; }
}

// ---------------- Layer-2 edge kernel: single-pass -> final logits --------
__global__ __launch_bounds__(256) void l2_edge_kernel(
    const int* __restrict__ offsets, const int* __restrict__ counts,
    const int* __restrict__ csr,
    const float* __restrict__ asrc2, const float* __restrict__ adst2,
    const float* __restrict__ h2, const float* __restrict__ b2,
    float* __restrict__ out, int n)
{
    int t = threadIdx.x, lane = t & 63;
    int node = blockIdx.x * 4 + (t >> 6);
    if (node >= n) return;
    int beg = offsets[node];
    int deg = counts[node];
    float adv = adst2[node];

    int c = lane & 7, slot = lane >> 3;
    float acc = 0.f, ssum = 0.f;
    if (slot == 0) {
        float e = asrc2[node] + adv;
        e = e > 0.f ? e : NEG_SLOPE * e;
        float p = __expf(e);
        acc = p * h2[node * 8 + c];
        ssum = p;
    }
    int j = slot;
    for (; j + 8 < deg; j += 16) {
        int s0 = csr[beg + j], s1 = csr[beg + j + 8];
        float a0 = asrc2[s0], a1 = asrc2[s1];
        float g0 = h2[s0 * 8 + c], g1 = h2[s1 * 8 + c];
        float e0 = a0 + adv; e0 = e0 > 0.f ? e0 : NEG_SLOPE * e0;
        float e1 = a1 + adv; e1 = e1 > 0.f ? e1 : NEG_SLOPE * e1;
        float p0 = __expf(e0), p1 = __expf(e1);
        acc = fmaf(p0, g0, acc); acc = fmaf(p1, g1, acc);
        ssum += p0 + p1;
    }
    for (; j < deg; j += 8) {
        int sn = csr[beg + j];
        float e = asrc2[sn] + adv;
        e = e > 0.f ? e : NEG_SLOPE * e;
        float p = __expf(e);
        acc = fmaf(p, h2[sn * 8 + c], acc);
        ssum += p;
    }
    acc  += __shfl_xor(acc, 8);  acc  += __shfl_xor(acc, 16);  acc  += __shfl_xor(acc, 32);
    ssum += __shfl_xor(ssum, 8); ssum += __shfl_xor(ssum, 16); ssum += __shfl_xor(ssum, 32);
    float inv = 1.f / fmaxf(ssum, 1e-16f);
    if (lane < OUT_DIM) out[(size_t)node * OUT_DIM + lane] = acc * inv + b2[lane];
}

// ---------------- launch ----------------
static inline size_t rup256(size_t x) { return (x + 255) & ~(size_t)255; }

extern "C" void kernel_launch(void* const* d_in, const int* in_sizes, int n_in,
                              void* d_out, int out_size, void* d_ws, size_t ws_size,
                              hipStream_t stream)
{
    int n = in_sizes[0] / IN_DIM;       // 50000
    int E = in_sizes[1] / 2;            // 1600000
    int nbuck = (n + BMASK) >> BSHIFT;  // 391
    int nCoarse = (E + 256 * K3_EPT - 1) / (256 * K3_EPT);   // 391

    const float* x   = (const float*)d_in[0];
    const int*   ei  = (const int*)d_in[1];
    const int*   srcv = ei;
    const int*   dstv = ei + E;
    const float* W1  = (const float*)d_in[2];
    const float* as1 = (const float*)d_in[3];
    const float* ad1 = (const float*)d_in[4];
    const float* b1  = (const float*)d_in[5];
    const float* W2  = (const float*)d_in[6];
    const float* as2 = (const float*)d_in[7];
    const float* ad2 = (const float*)d_in[8];
    const float* b2  = (const float*)d_in[9];
    float* out = (float*)d_out;

    char* p = (char*)d_ws;
    auto alloc = [&](size_t bytes) { char* q = p; p += rup256(bytes); return (void*)q; };
    unsigned short* h1 = (unsigned short*)alloc((size_t)n * 64 * 2);
    float* asrc1   = (float*)alloc((size_t)n * 8 * 4);
    float* adst1   = (float*)alloc((size_t)n * 8 * 4);
    float* h2      = (float*)alloc((size_t)n * 8 * 4);
    float* asrc2   = (float*)alloc((size_t)n * 4);
    float* adst2   = (float*)alloc((size_t)n * 4);
    int*   counts  = (int*)alloc((size_t)n * 4);
    int*   offsets = (int*)alloc(((size_t)n + 1) * 4);
    int*   csr     = (int*)alloc((size_t)E * 4);
    unsigned int* tmp = (unsigned int*)alloc((size_t)E * 4);
    int*   bucketCounts = (int*)alloc(512 * 4);
    int*   bucketBase   = (int*)alloc(513 * 4);
    int*   bucketCursor = (int*)alloc(512 * 4);
    unsigned short* bhi = (unsigned short*)alloc((size_t)IN_DIM * 64 * 2);
    unsigned short* blo = (unsigned short*)alloc((size_t)IN_DIM * 64 * 2);

    hipMemsetAsync(bucketCounts, 0, 512 * 4, stream);
    prep_kernel<<<128 + 512, 256, 0, stream>>>(W1, bhi, blo, dstv, bucketCounts, E, nbuck);
    bucket_scan_kernel<<<1, 512, 0, stream>>>(bucketCounts, bucketBase, bucketCursor, nbuck);
    gemm1_coarse_kernel<<<nCoarse + (n + 15) / 16, 256, 0, stream>>>(
        x, bhi, blo, as1, ad1, h1, asrc1, adst1, n,
        srcv, dstv, bucketCursor, tmp, E, nCoarse);
    fine_scatter_kernel<<<nbuck, 256, 0, stream>>>(
        tmp, bucketBase, csr, offsets, counts, n);
    l1_edge_kernel<<<(n + 3) / 4, 256, 0, stream>>>(
        offsets, counts, csr, asrc1, adst1, h1, b1, W2, as2, ad2, h2, asrc2, adst2, n);
    l2_edge_kernel<<<(n + 3) / 4, 256, 0, stream>>>(
        offsets, counts, csr, asrc2, adst2, h2, b2, out, n);
}